// Round 1
// baseline (466.344 us; speedup 1.0000x reference)
//
#include <hip/hip_runtime.h>
#include <hip/hip_bf16.h>
#include <stdint.h>

#define DEV static __device__ __forceinline__

typedef __attribute__((ext_vector_type(4))) float  f32x4;
typedef __attribute__((ext_vector_type(8))) __bf16 bf16x8;
typedef __attribute__((ext_vector_type(8))) unsigned short u16x8;
typedef __attribute__((ext_vector_type(4))) unsigned short u16x4;
typedef __attribute__((ext_vector_type(4))) float  fvec4;

DEV unsigned short f2b(float f) {
  union { float f; unsigned int u; } v; v.f = f;
  unsigned int r = v.u + 0x7fffu + ((v.u >> 16) & 1u);
  return (unsigned short)(r >> 16);
}
DEV float b2f(unsigned short b) {
  union { unsigned int u; float f; } v; v.u = ((unsigned int)b) << 16;
  return v.f;
}

// async global->LDS, 16B per lane. LDS dest must be wave-uniform base + lane*16.
DEV void gload_lds16(const void* g, void* l) {
  __builtin_amdgcn_global_load_lds(
      (__attribute__((address_space(1))) void*)(uintptr_t)g,
      (__attribute__((address_space(3))) void*)(uintptr_t)l, 16, 0, 0);
}

// ---------------- prep kernels ----------------

__global__ void convert_bf16x4(const float* __restrict__ in,
                               unsigned short* __restrict__ out, int n4) {
  int i = blockIdx.x * 256 + threadIdx.x;
  if (i >= n4) return;
  fvec4 v = *(const fvec4*)&in[(size_t)i * 4];
  u16x4 o;
  o[0] = f2b(v[0]); o[1] = f2b(v[1]); o[2] = f2b(v[2]); o[3] = f2b(v[3]);
  *(u16x4*)&out[(size_t)i * 4] = o;
}

// out[c][r] = (bf16) in[r][c];  in: R x C fp32, out: C x R bf16
__global__ void transpose_f2b(const float* __restrict__ in,
                              unsigned short* __restrict__ out, int R, int C) {
  __shared__ float t[32][33];
  int c0 = blockIdx.x * 32, r0 = blockIdx.y * 32;
  int tx = threadIdx.x & 31, ty = threadIdx.x >> 5;  // ty: 0..7
#pragma unroll
  for (int i = 0; i < 32; i += 8)
    t[ty + i][tx] = in[(size_t)(r0 + ty + i) * C + c0 + tx];
  __syncthreads();
#pragma unroll
  for (int i = 0; i < 32; i += 8)
    out[(size_t)(c0 + ty + i) * R + r0 + tx] = f2b(t[tx][ty + i]);
}

__global__ void rope_table(const float* __restrict__ r, float* __restrict__ c,
                           float* __restrict__ s, int n) {
  int i = blockIdx.x * 256 + threadIdx.x;
  if (i < n) { float v = r[i]; c[i] = cosf(v); s[i] = sinf(v); }
}

// ---------------- GEMM: C = A(MxK) * Bt(NxK)^T, bf16 MFMA ----------------
// EPI 0: scatter to q/k/v [B][H][L][hd] bf16 (+bias).  EPI 1: fp32 out (+bias).
template <int EPI>
__global__ __launch_bounds__(256) void gemm128(
    const unsigned short* __restrict__ A, const unsigned short* __restrict__ Bt,
    const float* __restrict__ bias,
    unsigned short* __restrict__ qo, unsigned short* __restrict__ ko,
    unsigned short* __restrict__ vo, float* __restrict__ outf,
    int M, int N, int K) {
  __shared__ __align__(16) unsigned short As[128 * 64];
  __shared__ __align__(16) unsigned short Bs[128 * 64];
  const int tid = threadIdx.x;
  const int lane = tid & 63, wave = tid >> 6;
  const int wr = wave >> 1, wc = wave & 1;
  const int g = lane >> 4, lr = lane & 15;
  const int m0 = blockIdx.y * 128, n0 = blockIdx.x * 128;

  f32x4 acc[4][4];
#pragma unroll
  for (int i = 0; i < 4; ++i)
#pragma unroll
    for (int j = 0; j < 4; ++j) acc[i][j] = f32x4{0.f, 0.f, 0.f, 0.f};

  for (int k0 = 0; k0 < K; k0 += 64) {
    // stage A,B tiles: linear LDS dest, inverse-XOR-swizzled global source
#pragma unroll
    for (int it = 0; it < 4; ++it) {
      int e = (it * 256 + tid) * 8;         // elem index in 128x64 tile
      int r = e >> 6, p = (e >> 3) & 7;     // row, 16B-chunk in row
      int sc = ((p ^ (r & 7)) << 3);        // source column (elems)
      gload_lds16(&A[(size_t)(m0 + r) * K + k0 + sc], &As[e]);
      gload_lds16(&Bt[(size_t)(n0 + r) * K + k0 + sc], &Bs[e]);
    }
    __syncthreads();  // compiler drains vmcnt before barrier
#pragma unroll
    for (int kk = 0; kk < 2; ++kk) {
      bf16x8 av[4], bv[4];
#pragma unroll
      for (int mf = 0; mf < 4; ++mf) {
        int row = wr * 64 + mf * 16 + lr;
        int ch = (kk * 4 + g) ^ (row & 7);
        av[mf] = *(const bf16x8*)&As[row * 64 + ch * 8];
      }
#pragma unroll
      for (int nf = 0; nf < 4; ++nf) {
        int row = wc * 64 + nf * 16 + lr;
        int ch = (kk * 4 + g) ^ (row & 7);
        bv[nf] = *(const bf16x8*)&Bs[row * 64 + ch * 8];
      }
#pragma unroll
      for (int mf = 0; mf < 4; ++mf)
#pragma unroll
        for (int nf = 0; nf < 4; ++nf)
          acc[mf][nf] = __builtin_amdgcn_mfma_f32_16x16x32_bf16(
              av[mf], bv[nf], acc[mf][nf], 0, 0, 0);
    }
    __syncthreads();
  }

  if (EPI == 0) {
#pragma unroll
    for (int nf = 0; nf < 4; ++nf) {
      int col = n0 + wc * 64 + nf * 16 + lr;
      float bvv = bias[col];
      int s = col / 1280;
      int rem = col - s * 1280;
      int h = rem / 80, d = rem - h * 80;
      unsigned short* dst = (s == 0) ? qo : ((s == 1) ? ko : vo);
#pragma unroll
      for (int mf = 0; mf < 4; ++mf) {
#pragma unroll
        for (int r = 0; r < 4; ++r) {
          int row = m0 + wr * 64 + mf * 16 + g * 4 + r;
          int b = row >> 10, l = row & 1023;
          dst[((size_t)(b * 16 + h) * 1024 + l) * 80 + d] =
              f2b(acc[mf][nf][r] + bvv);
        }
      }
    }
  } else {
#pragma unroll
    for (int mf = 0; mf < 4; ++mf) {
#pragma unroll
      for (int r = 0; r < 4; ++r) {
        int row = m0 + wr * 64 + mf * 16 + g * 4 + r;
#pragma unroll
        for (int nf = 0; nf < 4; ++nf) {
          int col = n0 + wc * 64 + nf * 16 + lr;
          outf[(size_t)row * N + col] = acc[mf][nf][r] + bias[col];
        }
      }
    }
  }
}

// ---------------- RoPE in place on q,k ([B*H*L][80] bf16) ----------------
__global__ void rope_apply(unsigned short* __restrict__ q0,
                           unsigned short* __restrict__ q1,
                           const float* __restrict__ cosT,
                           const float* __restrict__ sinT) {
  int i = blockIdx.x * 256 + threadIdx.x;     // 2 arrays * 131072 rows * 5 chunks
  if (i >= 2 * 131072 * 5) return;
  unsigned short* arr = (i < 131072 * 5) ? q0 : q1;
  int rem = (i < 131072 * 5) ? i : (i - 131072 * 5);
  int row = rem / 5, c = rem - (rem / 5) * 5;
  int l = row & 1023;
  size_t base = (size_t)row * 80 + c * 8;
  u16x8 x1 = *(const u16x8*)&arr[base];
  u16x8 x2 = *(const u16x8*)&arr[base + 40];
  const float* cp = &cosT[l * 40 + c * 8];
  const float* sp = &sinT[l * 40 + c * 8];
  u16x8 y1, y2;
#pragma unroll
  for (int j = 0; j < 8; ++j) {
    float a = b2f(x1[j]), b = b2f(x2[j]);
    float cc = cp[j], ss = sp[j];
    y1[j] = f2b(a * cc - b * ss);
    y2[j] = f2b(b * cc + a * ss);
  }
  *(u16x8*)&arr[base] = y1;
  *(u16x8*)&arr[base + 40] = y2;
}

// ---------------- causal flash attention ----------------
// q,k,v: [B][H][1024][80] bf16 ; o: [B][1024][16*80] bf16
__global__ __launch_bounds__(256) void attn_fwd(
    const unsigned short* __restrict__ q, const unsigned short* __restrict__ k,
    const unsigned short* __restrict__ v, unsigned short* __restrict__ o) {
  __shared__ __align__(16) unsigned short Qs[64 * 128];  // rows padded to 96, pitch 128, XOR-swz
  __shared__ __align__(16) unsigned short Ks[64 * 128];
  __shared__ __align__(16) unsigned short Vt[80 * 72];   // V transposed, pitch 72
  __shared__ __align__(16) unsigned short Ps[4][16 * 72];

  const int tid = threadIdx.x, lane = tid & 63, wave = tid >> 6;
  const int g = lane >> 4, lr = lane & 15;
  const int qi = blockIdx.x, bh = blockIdx.y;
  const int b = bh >> 4, h = bh & 15;
  const size_t headBase = (size_t)bh * 1024 * 80;
  const int qbase = qi * 64;
  const u16x8 zero8 = {0, 0, 0, 0, 0, 0, 0, 0};

  // stage Q tile (zero-pad cols 80..95); chunks 12..15 never read
  for (int i = tid; i < 64 * 12; i += 256) {
    int l = i / 12, c = i - (i / 12) * 12;
    u16x8 val = zero8;
    if (c < 10) val = *(const u16x8*)&q[headBase + (size_t)(qbase + l) * 80 + c * 8];
    int pc = c ^ (l & 7);
    *(u16x8*)&Qs[l * 128 + pc * 8] = val;
  }

  float m_r[4], l_r[4];
  f32x4 o_acc[5];
#pragma unroll
  for (int r = 0; r < 4; ++r) { m_r[r] = -INFINITY; l_r[r] = 0.f; }
#pragma unroll
  for (int of = 0; of < 5; ++of) o_acc[of] = f32x4{0.f, 0.f, 0.f, 0.f};

  for (int kv = 0; kv <= qi; ++kv) {
    __syncthreads();  // prior reads of Ks/Vt done (also orders Q stage, iter 0)
    int kvbase = kv * 64;
    for (int i = tid; i < 64 * 12; i += 256) {
      int l = i / 12, c = i - (i / 12) * 12;
      u16x8 val = zero8;
      if (c < 10) val = *(const u16x8*)&k[headBase + (size_t)(kvbase + l) * 80 + c * 8];
      int pc = c ^ (l & 7);
      *(u16x8*)&Ks[l * 128 + pc * 8] = val;
    }
    for (int i = tid; i < 640; i += 256) {  // V transpose-stage, l fastest (2-way banks)
      int l = i & 63, c = i >> 6;
      u16x8 val = *(const u16x8*)&v[headBase + (size_t)(kvbase + l) * 80 + c * 8];
#pragma unroll
      for (int j = 0; j < 8; ++j) Vt[(c * 8 + j) * 72 + l] = val[j];
    }
    __syncthreads();

    // S = Q K^T for this wave's 16 q-rows x 64 k-cols
    f32x4 s[4];
#pragma unroll
    for (int nf = 0; nf < 4; ++nf) s[nf] = f32x4{0.f, 0.f, 0.f, 0.f};
#pragma unroll
    for (int kp = 0; kp < 3; ++kp) {
      int qrow = wave * 16 + lr;
      bf16x8 a = *(const bf16x8*)&Qs[qrow * 128 + ((kp * 4 + g) ^ (qrow & 7)) * 8];
#pragma unroll
      for (int nf = 0; nf < 4; ++nf) {
        int krow = nf * 16 + lr;
        bf16x8 bb = *(const bf16x8*)&Ks[krow * 128 + ((kp * 4 + g) ^ (krow & 7)) * 8];
        s[nf] = __builtin_amdgcn_mfma_f32_16x16x32_bf16(a, bb, s[nf], 0, 0, 0);
      }
    }

    // online softmax (D-layout: col=lr, row=g*4+r)
    const float scale = 0.11180339887498949f;
    float sv[4][4];
    float mt[4] = {-INFINITY, -INFINITY, -INFINITY, -INFINITY};
#pragma unroll
    for (int nf = 0; nf < 4; ++nf) {
      int kcol = kvbase + nf * 16 + lr;
#pragma unroll
      for (int r = 0; r < 4; ++r) {
        int qrow = qbase + wave * 16 + g * 4 + r;
        float x = s[nf][r] * scale;
        if (kcol > qrow) x = -INFINITY;
        sv[nf][r] = x;
        mt[r] = fmaxf(mt[r], x);
      }
    }
#pragma unroll
    for (int r = 0; r < 4; ++r) {
      mt[r] = fmaxf(mt[r], __shfl_xor(mt[r], 1, 64));
      mt[r] = fmaxf(mt[r], __shfl_xor(mt[r], 2, 64));
      mt[r] = fmaxf(mt[r], __shfl_xor(mt[r], 4, 64));
      mt[r] = fmaxf(mt[r], __shfl_xor(mt[r], 8, 64));
    }
    float fr[4];
#pragma unroll
    for (int r = 0; r < 4; ++r) {
      float mn = fmaxf(m_r[r], mt[r]);   // mt finite: col kvbase<=qrow always
      fr[r] = __expf(m_r[r] - mn);
      m_r[r] = mn;
    }
    float lt[4] = {0.f, 0.f, 0.f, 0.f};
#pragma unroll
    for (int nf = 0; nf < 4; ++nf)
#pragma unroll
      for (int r = 0; r < 4; ++r) {
        float p = __expf(sv[nf][r] - m_r[r]);
        sv[nf][r] = p;
        lt[r] += p;
      }
#pragma unroll
    for (int r = 0; r < 4; ++r) {
      lt[r] += __shfl_xor(lt[r], 1, 64);
      lt[r] += __shfl_xor(lt[r], 2, 64);
      lt[r] += __shfl_xor(lt[r], 4, 64);
      lt[r] += __shfl_xor(lt[r], 8, 64);
      l_r[r] = l_r[r] * fr[r] + lt[r];
    }
#pragma unroll
    for (int of = 0; of < 5; ++of)
#pragma unroll
      for (int r = 0; r < 4; ++r) o_acc[of][r] *= fr[r];

    // P (D-layout) -> per-wave LDS -> A-layout fragments
#pragma unroll
    for (int nf = 0; nf < 4; ++nf)
#pragma unroll
      for (int r = 0; r < 4; ++r)
        Ps[wave][(g * 4 + r) * 72 + nf * 16 + lr] = f2b(sv[nf][r]);
    asm volatile("s_waitcnt lgkmcnt(0)" ::: "memory");

#pragma unroll
    for (int kk = 0; kk < 2; ++kk) {
      bf16x8 pa = *(const bf16x8*)&Ps[wave][lr * 72 + kk * 32 + g * 8];
#pragma unroll
      for (int of = 0; of < 5; ++of) {
        bf16x8 vv = *(const bf16x8*)&Vt[(of * 16 + lr) * 72 + kk * 32 + g * 8];
        o_acc[of] = __builtin_amdgcn_mfma_f32_16x16x32_bf16(pa, vv, o_acc[of], 0, 0, 0);
      }
    }
  }

  // epilogue: O[b][l][h*80+d] bf16
#pragma unroll
  for (int of = 0; of < 5; ++of) {
#pragma unroll
    for (int r = 0; r < 4; ++r) {
      int lrow = qbase + wave * 16 + g * 4 + r;
      float val = o_acc[of][r] / l_r[r];
      o[((size_t)b * 1024 + lrow) * 1280 + h * 80 + of * 16 + lr] = f2b(val);
    }
  }
}

// ---------------- launcher ----------------
extern "C" void kernel_launch(void* const* d_in, const int* in_sizes, int n_in,
                              void* d_out, int out_size, void* d_ws, size_t ws_size,
                              hipStream_t stream) {
  const float* X     = (const float*)d_in[0];
  const float* rp    = (const float*)d_in[1];
  const float* Wqkv  = (const float*)d_in[2];
  const float* bqkv  = (const float*)d_in[3];
  const float* Wproj = (const float*)d_in[4];
  const float* bproj = (const float*)d_in[5];
  float* out = (float*)d_out;

  char* ws = (char*)d_ws;
  unsigned short* Xb     = (unsigned short*)(ws);              // 20971520 B (reused as Ob)
  unsigned short* Wqkvt  = (unsigned short*)(ws + 20971520);   // 9830400 B
  unsigned short* Wprojt = (unsigned short*)(ws + 30801920);   // 3276800 B
  float*          cosT   = (float*)(ws + 34078720);            // 163840 B
  float*          sinT   = (float*)(ws + 34242560);            // 163840 B
  unsigned short* vb     = (unsigned short*)(ws + 34406400);   // 20971520 B (total 55.4 MB)
  unsigned short* qb     = (unsigned short*)d_out;             // q,k live in d_out until proj
  unsigned short* kb     = qb + 10485760;
  unsigned short* Ob     = Xb;

  convert_bf16x4<<<10240, 256, 0, stream>>>(X, Xb, 2621440);
  transpose_f2b<<<dim3(120, 40), 256, 0, stream>>>(Wqkv, Wqkvt, 1280, 3840);
  transpose_f2b<<<dim3(40, 40), 256, 0, stream>>>(Wproj, Wprojt, 1280, 1280);
  rope_table<<<160, 256, 0, stream>>>(rp, cosT, sinT, 40960);
  gemm128<0><<<dim3(30, 64), 256, 0, stream>>>(Xb, Wqkvt, bqkv, qb, kb, vb,
                                               nullptr, 8192, 3840, 1280);
  rope_apply<<<5120, 256, 0, stream>>>(qb, kb, cosT, sinT);
  attn_fwd<<<dim3(16, 128), 256, 0, stream>>>(qb, kb, vb, Ob);
  gemm128<1><<<dim3(10, 64), 256, 0, stream>>>(Ob, Wprojt, bproj, nullptr,
                                               nullptr, nullptr, out, 8192, 1280, 1280);
}

// Round 2
// 412.038 us; speedup vs baseline: 1.1318x; 1.1318x over previous
//
#include <hip/hip_runtime.h>
#include <hip/hip_bf16.h>
#include <stdint.h>

#define DEV static __device__ __forceinline__

typedef __attribute__((ext_vector_type(4))) float  f32x4;
typedef __attribute__((ext_vector_type(8))) __bf16 bf16x8;
typedef __attribute__((ext_vector_type(8))) unsigned short u16x8;
typedef __attribute__((ext_vector_type(4))) unsigned short u16x4;
typedef __attribute__((ext_vector_type(4))) float  fvec4;

// scale(1/sqrt(80)) * log2(e) — folded into Q during RoPE; softmax in exp2 domain
#define SC2F 0.16129870963914802f

DEV unsigned short f2b(float f) {            // native RNE cvt (compiler emits v_cvt)
  __bf16 h = (__bf16)f;
  unsigned short u; __builtin_memcpy(&u, &h, 2);
  return u;
}
DEV float b2f(unsigned short b) {
  union { unsigned int u; float f; } v; v.u = ((unsigned int)b) << 16;
  return v.f;
}
DEV bf16x8 bzero8() {
  u16x8 z = 0; bf16x8 r; __builtin_memcpy(&r, &z, 16); return r;
}

DEV void gload_lds16(const void* g, void* l) {
  __builtin_amdgcn_global_load_lds(
      (__attribute__((address_space(1))) void*)(uintptr_t)g,
      (__attribute__((address_space(3))) void*)(uintptr_t)l, 16, 0, 0);
}

// ---------------- prep kernels ----------------

__global__ void convert_bf16x4(const float* __restrict__ in,
                               unsigned short* __restrict__ out, int n4) {
  int i = blockIdx.x * 256 + threadIdx.x;
  if (i >= n4) return;
  fvec4 v = *(const fvec4*)&in[(size_t)i * 4];
  u16x4 o;
  o[0] = f2b(v[0]); o[1] = f2b(v[1]); o[2] = f2b(v[2]); o[3] = f2b(v[3]);
  *(u16x4*)&out[(size_t)i * 4] = o;
}

__global__ void transpose_f2b(const float* __restrict__ in,
                              unsigned short* __restrict__ out, int R, int C) {
  __shared__ float t[32][33];
  int c0 = blockIdx.x * 32, r0 = blockIdx.y * 32;
  int tx = threadIdx.x & 31, ty = threadIdx.x >> 5;
#pragma unroll
  for (int i = 0; i < 32; i += 8)
    t[ty + i][tx] = in[(size_t)(r0 + ty + i) * C + c0 + tx];
  __syncthreads();
#pragma unroll
  for (int i = 0; i < 32; i += 8)
    out[(size_t)(c0 + ty + i) * R + r0 + tx] = f2b(t[tx][ty + i]);
}

__global__ void rope_table(const float* __restrict__ r, float* __restrict__ c,
                           float* __restrict__ s, int n) {
  int i = blockIdx.x * 256 + threadIdx.x;
  if (i < n) { float v = r[i]; c[i] = cosf(v); s[i] = sinf(v); }
}

// ---------------- GEMM: C = A(MxK) * Bt(NxK)^T, bf16 MFMA ----------------
template <int EPI>
__global__ __launch_bounds__(256) void gemm128(
    const unsigned short* __restrict__ A, const unsigned short* __restrict__ Bt,
    const float* __restrict__ bias,
    unsigned short* __restrict__ qo, unsigned short* __restrict__ ko,
    unsigned short* __restrict__ vo, float* __restrict__ outf,
    int M, int N, int K) {
  __shared__ __align__(16) unsigned short As[128 * 64];
  __shared__ __align__(16) unsigned short Bs[128 * 64];
  const int tid = threadIdx.x;
  const int lane = tid & 63, wave = tid >> 6;
  const int wr = wave >> 1, wc = wave & 1;
  const int g = lane >> 4, lr = lane & 15;
  const int m0 = blockIdx.y * 128, n0 = blockIdx.x * 128;

  f32x4 acc[4][4];
#pragma unroll
  for (int i = 0; i < 4; ++i)
#pragma unroll
    for (int j = 0; j < 4; ++j) acc[i][j] = f32x4{0.f, 0.f, 0.f, 0.f};

  for (int k0 = 0; k0 < K; k0 += 64) {
#pragma unroll
    for (int it = 0; it < 4; ++it) {
      int e = (it * 256 + tid) * 8;
      int r = e >> 6, p = (e >> 3) & 7;
      int sc = ((p ^ (r & 7)) << 3);
      gload_lds16(&A[(size_t)(m0 + r) * K + k0 + sc], &As[e]);
      gload_lds16(&Bt[(size_t)(n0 + r) * K + k0 + sc], &Bs[e]);
    }
    __syncthreads();
#pragma unroll
    for (int kk = 0; kk < 2; ++kk) {
      bf16x8 av[4], bv[4];
#pragma unroll
      for (int mf = 0; mf < 4; ++mf) {
        int row = wr * 64 + mf * 16 + lr;
        int ch = (kk * 4 + g) ^ (row & 7);
        av[mf] = *(const bf16x8*)&As[row * 64 + ch * 8];
      }
#pragma unroll
      for (int nf = 0; nf < 4; ++nf) {
        int row = wc * 64 + nf * 16 + lr;
        int ch = (kk * 4 + g) ^ (row & 7);
        bv[nf] = *(const bf16x8*)&Bs[row * 64 + ch * 8];
      }
#pragma unroll
      for (int mf = 0; mf < 4; ++mf)
#pragma unroll
        for (int nf = 0; nf < 4; ++nf)
          acc[mf][nf] = __builtin_amdgcn_mfma_f32_16x16x32_bf16(
              av[mf], bv[nf], acc[mf][nf], 0, 0, 0);
    }
    __syncthreads();
  }

  if (EPI == 0) {
#pragma unroll
    for (int nf = 0; nf < 4; ++nf) {
      int col = n0 + wc * 64 + nf * 16 + lr;
      float bvv = bias[col];
      int s = col / 1280;
      int rem = col - s * 1280;
      int h = rem / 80, d = rem - h * 80;
      unsigned short* dst = (s == 0) ? qo : ((s == 1) ? ko : vo);
#pragma unroll
      for (int mf = 0; mf < 4; ++mf) {
#pragma unroll
        for (int r = 0; r < 4; ++r) {
          int row = m0 + wr * 64 + mf * 16 + g * 4 + r;
          int b = row >> 10, l = row & 1023;
          dst[((size_t)(b * 16 + h) * 1024 + l) * 80 + d] =
              f2b(acc[mf][nf][r] + bvv);
        }
      }
    }
  } else {
#pragma unroll
    for (int mf = 0; mf < 4; ++mf) {
#pragma unroll
      for (int r = 0; r < 4; ++r) {
        int row = m0 + wr * 64 + mf * 16 + g * 4 + r;
#pragma unroll
        for (int nf = 0; nf < 4; ++nf) {
          int col = n0 + wc * 64 + nf * 16 + lr;
          outf[(size_t)row * N + col] = acc[mf][nf][r] + bias[col];
        }
      }
    }
  }
}

// ---------------- RoPE in place; q additionally scaled by SC2F ----------------
__global__ void rope_apply(unsigned short* __restrict__ q0,
                           unsigned short* __restrict__ q1,
                           const float* __restrict__ cosT,
                           const float* __restrict__ sinT) {
  int i = blockIdx.x * 256 + threadIdx.x;
  if (i >= 2 * 131072 * 5) return;
  bool isq = (i < 131072 * 5);
  unsigned short* arr = isq ? q0 : q1;
  float sc = isq ? SC2F : 1.0f;
  int rem = isq ? i : (i - 131072 * 5);
  int row = rem / 5, c = rem - (rem / 5) * 5;
  int l = row & 1023;
  size_t base = (size_t)row * 80 + c * 8;
  u16x8 x1 = *(const u16x8*)&arr[base];
  u16x8 x2 = *(const u16x8*)&arr[base + 40];
  const float* cp = &cosT[l * 40 + c * 8];
  const float* sp = &sinT[l * 40 + c * 8];
  u16x8 y1, y2;
#pragma unroll
  for (int j = 0; j < 8; ++j) {
    float a = b2f(x1[j]), b = b2f(x2[j]);
    float cc = cp[j], ss = sp[j];
    y1[j] = f2b((a * cc - b * ss) * sc);
    y2[j] = f2b((b * cc + a * ss) * sc);
  }
  *(u16x8*)&arr[base] = y1;
  *(u16x8*)&arr[base + 40] = y2;
}

// ---------------- causal flash attention (QBLK=128, KVBLK=64) ----------------
// q (pre-scaled by SC2F), k, v: [B*H][1024][80] bf16 ; o: [B][1024][1280] bf16
__global__ __launch_bounds__(256, 3) void attn_fwd(
    const unsigned short* __restrict__ q, const unsigned short* __restrict__ k,
    const unsigned short* __restrict__ v, unsigned short* __restrict__ o) {
  __shared__ __align__(16) unsigned short Ks[64 * 80];   // pitch 80: naturally staggered banks
  __shared__ __align__(16) unsigned short Vt[80 * 72];   // V^T, pitch 72 (144B rows)
  __shared__ __align__(16) unsigned short Ps[4][32 * 88];// pitch 88 (176B rows)

  const int tid = threadIdx.x, lane = tid & 63, wave = tid >> 6;
  const int g = lane >> 4, lr = lane & 15;
  const int bid = blockIdx.x;
  const int qi = 7 - (bid >> 7);        // long blocks first (load balance)
  const int bh = bid & 127;
  const int b = bh >> 4, h = bh & 15;
  const size_t headBase = (size_t)bh * 1024 * 80;
  const int qbase = qi * 128;
  const int wmin = qbase + wave * 32;

  // ---- Q fragments in registers (once) ----
  bf16x8 qf[2][2], qf2[2];
#pragma unroll
  for (int mf = 0; mf < 2; ++mf) {
    const unsigned short* qr = q + headBase + (size_t)(wmin + mf * 16 + lr) * 80;
    qf[mf][0] = *(const bf16x8*)(qr + g * 8);
    qf[mf][1] = *(const bf16x8*)(qr + 32 + g * 8);
    bf16x8 t = *(const bf16x8*)(qr + 64 + (g & 1) * 8);
    if (g >= 2) t = bzero8();           // zero k in [80,96): kills padded products
    qf2[mf] = t;
  }

  float m_r[2][4], l_r[2][4];
  f32x4 o_acc[2][5];
#pragma unroll
  for (int mf = 0; mf < 2; ++mf) {
#pragma unroll
    for (int r = 0; r < 4; ++r) { m_r[mf][r] = -INFINITY; l_r[mf][r] = 0.f; }
#pragma unroll
    for (int of = 0; of < 5; ++of) o_acc[mf][of] = f32x4{0.f, 0.f, 0.f, 0.f};
  }

  const int nkv = 2 * qi + 2;
  for (int kv = 0; kv < nkv; ++kv) {
    const int kvbase = kv * 64;
    __syncthreads();                    // prior-iter Ks/Vt reads done
    // K: straight linear 20KB copy (rows contiguous in global)
    for (int idx = tid; idx < 640; idx += 256)
      gload_lds16(&k[headBase + (size_t)kvbase * 80 + idx * 8], &Ks[idx * 8]);
    // V: transpose-stage
    for (int i = tid; i < 640; i += 256) {
      int l = i & 63, c = i >> 6;
      u16x8 val = *(const u16x8*)&v[headBase + (size_t)(kvbase + l) * 80 + c * 8];
#pragma unroll
      for (int j = 0; j < 8; ++j) Vt[(c * 8 + j) * 72 + l] = val[j];
    }
    __syncthreads();
    if (kvbase > wmin + 31) continue;   // fully-masked for this wave (uniform)
    const bool maskT = (kvbase + 63 > wmin);

    // ---- S = Q K^T : 24 MFMA ----
    f32x4 s[2][4];
#pragma unroll
    for (int mf = 0; mf < 2; ++mf)
#pragma unroll
      for (int nf = 0; nf < 4; ++nf) s[mf][nf] = f32x4{0.f, 0.f, 0.f, 0.f};
#pragma unroll
    for (int kp = 0; kp < 2; ++kp) {
#pragma unroll
      for (int nf = 0; nf < 4; ++nf) {
        bf16x8 kb = *(const bf16x8*)&Ks[(nf * 16 + lr) * 80 + kp * 32 + g * 8];
#pragma unroll
        for (int mf = 0; mf < 2; ++mf)
          s[mf][nf] = __builtin_amdgcn_mfma_f32_16x16x32_bf16(qf[mf][kp], kb,
                                                              s[mf][nf], 0, 0, 0);
      }
    }
#pragma unroll
    for (int nf = 0; nf < 4; ++nf) {    // k 64..79 (+garbage k80..95 × zero Q)
      bf16x8 kb = *(const bf16x8*)&Ks[(nf * 16 + lr) * 80 + 64 + (g & 1) * 8];
#pragma unroll
      for (int mf = 0; mf < 2; ++mf)
        s[mf][nf] = __builtin_amdgcn_mfma_f32_16x16x32_bf16(qf2[mf], kb,
                                                            s[mf][nf], 0, 0, 0);
    }

    // ---- online softmax (exp2 domain; scale pre-folded into Q) ----
    if (maskT) {
#pragma unroll
      for (int mf = 0; mf < 2; ++mf)
#pragma unroll
        for (int nf = 0; nf < 4; ++nf)
#pragma unroll
          for (int r = 0; r < 4; ++r)
            if (kvbase + nf * 16 + lr > wmin + mf * 16 + g * 4 + r)
              s[mf][nf][r] = -INFINITY;
    }
    float mt[2][4];
#pragma unroll
    for (int mf = 0; mf < 2; ++mf)
#pragma unroll
      for (int r = 0; r < 4; ++r)
        mt[mf][r] = fmaxf(fmaxf(s[mf][0][r], s[mf][1][r]),
                          fmaxf(s[mf][2][r], s[mf][3][r]));
#pragma unroll
    for (int d = 1; d <= 8; d <<= 1)
#pragma unroll
      for (int mf = 0; mf < 2; ++mf)
#pragma unroll
        for (int r = 0; r < 4; ++r)
          mt[mf][r] = fmaxf(mt[mf][r], __shfl_xor(mt[mf][r], d, 64));

    int ok = 1;
#pragma unroll
    for (int mf = 0; mf < 2; ++mf)
#pragma unroll
      for (int r = 0; r < 4; ++r) ok &= (mt[mf][r] <= m_r[mf][r] + 10.0f);
    const bool need = !__all(ok);       // defer-max: rescale only on real growth
    float fr[2][4];
    if (need) {
#pragma unroll
      for (int mf = 0; mf < 2; ++mf)
#pragma unroll
        for (int r = 0; r < 4; ++r) {
          float mn = fmaxf(m_r[mf][r], mt[mf][r]);
          fr[mf][r] = exp2f(m_r[mf][r] - mn);
          m_r[mf][r] = mn;
        }
    }
    float lt[2][4] = {{0.f, 0.f, 0.f, 0.f}, {0.f, 0.f, 0.f, 0.f}};
#pragma unroll
    for (int mf = 0; mf < 2; ++mf)
#pragma unroll
      for (int nf = 0; nf < 4; ++nf)
#pragma unroll
        for (int r = 0; r < 4; ++r) {
          float p = exp2f(s[mf][nf][r] - m_r[mf][r]);
          s[mf][nf][r] = p;
          lt[mf][r] += p;
        }
#pragma unroll
    for (int d = 1; d <= 8; d <<= 1)
#pragma unroll
      for (int mf = 0; mf < 2; ++mf)
#pragma unroll
        for (int r = 0; r < 4; ++r) lt[mf][r] += __shfl_xor(lt[mf][r], d, 64);
    if (need) {
#pragma unroll
      for (int mf = 0; mf < 2; ++mf)
#pragma unroll
        for (int r = 0; r < 4; ++r) l_r[mf][r] = l_r[mf][r] * fr[mf][r] + lt[mf][r];
#pragma unroll
      for (int mf = 0; mf < 2; ++mf)
#pragma unroll
        for (int of = 0; of < 5; ++of)
#pragma unroll
          for (int r = 0; r < 4; ++r) o_acc[mf][of][r] *= fr[mf][r];
    } else {
#pragma unroll
      for (int mf = 0; mf < 2; ++mf)
#pragma unroll
        for (int r = 0; r < 4; ++r) l_r[mf][r] += lt[mf][r];
    }

    // ---- P -> per-wave LDS (D-layout -> A-layout) ----
#pragma unroll
    for (int mf = 0; mf < 2; ++mf)
#pragma unroll
      for (int nf = 0; nf < 4; ++nf)
#pragma unroll
        for (int r = 0; r < 4; ++r)
          Ps[wave][(mf * 16 + g * 4 + r) * 88 + nf * 16 + lr] = f2b(s[mf][nf][r]);

    // ---- O += P V : 20 MFMA ----
#pragma unroll
    for (int kk = 0; kk < 2; ++kk) {
      bf16x8 pa[2];
#pragma unroll
      for (int mf = 0; mf < 2; ++mf)
        pa[mf] = *(const bf16x8*)&Ps[wave][(mf * 16 + lr) * 88 + kk * 32 + g * 8];
#pragma unroll
      for (int of = 0; of < 5; ++of) {
        bf16x8 vv = *(const bf16x8*)&Vt[(of * 16 + lr) * 72 + kk * 32 + g * 8];
#pragma unroll
        for (int mf = 0; mf < 2; ++mf)
          o_acc[mf][of] = __builtin_amdgcn_mfma_f32_16x16x32_bf16(pa[mf], vv,
                                                                  o_acc[mf][of], 0, 0, 0);
      }
    }
  }

  // ---- epilogue ----
#pragma unroll
  for (int mf = 0; mf < 2; ++mf) {
    float inv[4];
#pragma unroll
    for (int r = 0; r < 4; ++r) inv[r] = 1.0f / l_r[mf][r];
#pragma unroll
    for (int of = 0; of < 5; ++of)
#pragma unroll
      for (int r = 0; r < 4; ++r) {
        int row = wmin + mf * 16 + g * 4 + r;
        o[((size_t)b * 1024 + row) * 1280 + h * 80 + of * 16 + lr] =
            f2b(o_acc[mf][of][r] * inv[r]);
      }
  }
}

// ---------------- launcher ----------------
extern "C" void kernel_launch(void* const* d_in, const int* in_sizes, int n_in,
                              void* d_out, int out_size, void* d_ws, size_t ws_size,
                              hipStream_t stream) {
  const float* X     = (const float*)d_in[0];
  const float* rp    = (const float*)d_in[1];
  const float* Wqkv  = (const float*)d_in[2];
  const float* bqkv  = (const float*)d_in[3];
  const float* Wproj = (const float*)d_in[4];
  const float* bproj = (const float*)d_in[5];
  float* out = (float*)d_out;

  char* ws = (char*)d_ws;
  unsigned short* Xb     = (unsigned short*)(ws);              // 20971520 B (reused as Ob)
  unsigned short* Wqkvt  = (unsigned short*)(ws + 20971520);   // 9830400 B
  unsigned short* Wprojt = (unsigned short*)(ws + 30801920);   // 3276800 B
  float*          cosT   = (float*)(ws + 34078720);            // 163840 B
  float*          sinT   = (float*)(ws + 34242560);            // 163840 B
  unsigned short* vb     = (unsigned short*)(ws + 34406400);   // 20971520 B
  unsigned short* qb     = (unsigned short*)d_out;             // q,k live in d_out until proj
  unsigned short* kb     = qb + 10485760;
  unsigned short* Ob     = Xb;

  convert_bf16x4<<<10240, 256, 0, stream>>>(X, Xb, 2621440);
  transpose_f2b<<<dim3(120, 40), 256, 0, stream>>>(Wqkv, Wqkvt, 1280, 3840);
  transpose_f2b<<<dim3(40, 40), 256, 0, stream>>>(Wproj, Wprojt, 1280, 1280);
  rope_table<<<160, 256, 0, stream>>>(rp, cosT, sinT, 40960);
  gemm128<0><<<dim3(30, 64), 256, 0, stream>>>(Xb, Wqkvt, bqkv, qb, kb, vb,
                                               nullptr, 8192, 3840, 1280);
  rope_apply<<<5120, 256, 0, stream>>>(qb, kb, cosT, sinT);
  attn_fwd<<<1024, 256, 0, stream>>>(qb, kb, vb, Ob);
  gemm128<1><<<dim3(10, 64), 256, 0, stream>>>(Ob, Wprojt, bproj, nullptr,
                                               nullptr, nullptr, out, 8192, 1280, 1280);
}

// Round 4
// 373.332 us; speedup vs baseline: 1.2491x; 1.1037x over previous
//
#include <hip/hip_runtime.h>
#include <hip/hip_bf16.h>
#include <stdint.h>

#define DEV static __device__ __forceinline__

typedef __attribute__((ext_vector_type(4))) float  f32x4;
typedef __attribute__((ext_vector_type(8))) __bf16 bf16x8;
typedef __attribute__((ext_vector_type(8))) unsigned short u16x8;
typedef __attribute__((ext_vector_type(4))) unsigned short u16x4;
typedef __attribute__((ext_vector_type(4))) float  fvec4;

// scale(1/sqrt(80)) * log2(e) — folded into Q during RoPE; softmax in exp2 domain
#define SC2F 0.16129870963914802f

DEV unsigned short f2b(float f) {
  __bf16 h = (__bf16)f;
  unsigned short u; __builtin_memcpy(&u, &h, 2);
  return u;
}
DEV float b2f(unsigned short b) {
  union { unsigned int u; float f; } v; v.u = ((unsigned int)b) << 16;
  return v.f;
}
DEV bf16x8 bzero8() {
  u16x8 z = 0; bf16x8 r; __builtin_memcpy(&r, &z, 16); return r;
}

DEV void gload_lds16(const void* g, void* l) {
  __builtin_amdgcn_global_load_lds(
      (__attribute__((address_space(1))) void*)(uintptr_t)g,
      (__attribute__((address_space(3))) void*)(uintptr_t)l, 16, 0, 0);
}

// ---------------- prep kernels ----------------

__global__ void convert_bf16x4(const float* __restrict__ in,
                               unsigned short* __restrict__ out, int n4) {
  int i = blockIdx.x * 256 + threadIdx.x;
  if (i >= n4) return;
  fvec4 v = *(const fvec4*)&in[(size_t)i * 4];
  u16x4 o;
  o[0] = f2b(v[0]); o[1] = f2b(v[1]); o[2] = f2b(v[2]); o[3] = f2b(v[3]);
  *(u16x4*)&out[(size_t)i * 4] = o;
}

__global__ void transpose_f2b(const float* __restrict__ in,
                              unsigned short* __restrict__ out, int R, int C) {
  __shared__ float t[32][33];
  int c0 = blockIdx.x * 32, r0 = blockIdx.y * 32;
  int tx = threadIdx.x & 31, ty = threadIdx.x >> 5;
#pragma unroll
  for (int i = 0; i < 32; i += 8)
    t[ty + i][tx] = in[(size_t)(r0 + ty + i) * C + c0 + tx];
  __syncthreads();
#pragma unroll
  for (int i = 0; i < 32; i += 8)
    out[(size_t)(c0 + ty + i) * R + r0 + tx] = f2b(t[tx][ty + i]);
}

__global__ void rope_table(const float* __restrict__ r, float* __restrict__ c,
                           float* __restrict__ s, int n) {
  int i = blockIdx.x * 256 + threadIdx.x;
  if (i < n) { float v = r[i]; c[i] = cosf(v); s[i] = sinf(v); }
}

// ---------------- GEMM: C = A(MxK) * Bt(NxK)^T, bf16 MFMA ----------------
template <int EPI>
__global__ __launch_bounds__(256) void gemm128(
    const unsigned short* __restrict__ A, const unsigned short* __restrict__ Bt,
    const float* __restrict__ bias,
    unsigned short* __restrict__ qo, unsigned short* __restrict__ ko,
    unsigned short* __restrict__ vo, float* __restrict__ outf,
    int M, int N, int K) {
  __shared__ __align__(16) unsigned short As[128 * 64];
  __shared__ __align__(16) unsigned short Bs[128 * 64];
  const int tid = threadIdx.x;
  const int lane = tid & 63, wave = tid >> 6;
  const int wr = wave >> 1, wc = wave & 1;
  const int g = lane >> 4, lr = lane & 15;
  // bijective XCD swizzle (nwg % 8 == 0): contiguous chunk per XCD
  const int nwg = gridDim.x, cpx = nwg >> 3;
  const int swz = (blockIdx.x & 7) * cpx + (blockIdx.x >> 3);
  const int gx = N >> 7;
  const int bx = swz % gx, by = swz / gx;
  const int m0 = by * 128, n0 = bx * 128;

  f32x4 acc[4][4];
#pragma unroll
  for (int i = 0; i < 4; ++i)
#pragma unroll
    for (int j = 0; j < 4; ++j) acc[i][j] = f32x4{0.f, 0.f, 0.f, 0.f};

  for (int k0 = 0; k0 < K; k0 += 64) {
#pragma unroll
    for (int it = 0; it < 4; ++it) {
      int e = (it * 256 + tid) * 8;
      int r = e >> 6, p = (e >> 3) & 7;
      int sc = ((p ^ (r & 7)) << 3);
      gload_lds16(&A[(size_t)(m0 + r) * K + k0 + sc], &As[e]);
      gload_lds16(&Bt[(size_t)(n0 + r) * K + k0 + sc], &Bs[e]);
    }
    __syncthreads();
#pragma unroll
    for (int kk = 0; kk < 2; ++kk) {
      bf16x8 av[4], bv[4];
#pragma unroll
      for (int mf = 0; mf < 4; ++mf) {
        int row = wr * 64 + mf * 16 + lr;
        int ch = (kk * 4 + g) ^ (row & 7);
        av[mf] = *(const bf16x8*)&As[row * 64 + ch * 8];
      }
#pragma unroll
      for (int nf = 0; nf < 4; ++nf) {
        int row = wc * 64 + nf * 16 + lr;
        int ch = (kk * 4 + g) ^ (row & 7);
        bv[nf] = *(const bf16x8*)&Bs[row * 64 + ch * 8];
      }
#pragma unroll
      for (int mf = 0; mf < 4; ++mf)
#pragma unroll
        for (int nf = 0; nf < 4; ++nf)
          acc[mf][nf] = __builtin_amdgcn_mfma_f32_16x16x32_bf16(
              av[mf], bv[nf], acc[mf][nf], 0, 0, 0);
    }
    __syncthreads();
  }

  if (EPI == 0) {
#pragma unroll
    for (int nf = 0; nf < 4; ++nf) {
      int col = n0 + wc * 64 + nf * 16 + lr;
      float bvv = bias[col];
      int s = col / 1280;
      int rem = col - s * 1280;
      int h = rem / 80, d = rem - h * 80;
      unsigned short* dst = (s == 0) ? qo : ((s == 1) ? ko : vo);
#pragma unroll
      for (int mf = 0; mf < 4; ++mf) {
#pragma unroll
        for (int r = 0; r < 4; ++r) {
          int row = m0 + wr * 64 + mf * 16 + g * 4 + r;
          int b = row >> 10, l = row & 1023;
          dst[((size_t)(b * 16 + h) * 1024 + l) * 80 + d] =
              f2b(acc[mf][nf][r] + bvv);
        }
      }
    }
  } else {
#pragma unroll
    for (int mf = 0; mf < 4; ++mf) {
#pragma unroll
      for (int r = 0; r < 4; ++r) {
        int row = m0 + wr * 64 + mf * 16 + g * 4 + r;
#pragma unroll
        for (int nf = 0; nf < 4; ++nf) {
          int col = n0 + wc * 64 + nf * 16 + lr;
          outf[(size_t)row * N + col] = acc[mf][nf][r] + bias[col];
        }
      }
    }
  }
}

// ---------------- RoPE in place; q additionally scaled by SC2F ----------------
__global__ void rope_apply(unsigned short* __restrict__ q0,
                           unsigned short* __restrict__ q1,
                           const float* __restrict__ cosT,
                           const float* __restrict__ sinT) {
  int i = blockIdx.x * 256 + threadIdx.x;
  if (i >= 2 * 131072 * 5) return;
  bool isq = (i < 131072 * 5);
  unsigned short* arr = isq ? q0 : q1;
  float sc = isq ? SC2F : 1.0f;
  int rem = isq ? i : (i - 131072 * 5);
  int row = rem / 5, c = rem - (rem / 5) * 5;
  int l = row & 1023;
  size_t base = (size_t)row * 80 + c * 8;
  u16x8 x1 = *(const u16x8*)&arr[base];
  u16x8 x2 = *(const u16x8*)&arr[base + 40];
  const float* cp = &cosT[l * 40 + c * 8];
  const float* sp = &sinT[l * 40 + c * 8];
  u16x8 y1, y2;
#pragma unroll
  for (int j = 0; j < 8; ++j) {
    float a = b2f(x1[j]), b = b2f(x2[j]);
    float cc = cp[j], ss = sp[j];
    y1[j] = f2b((a * cc - b * ss) * sc);
    y2[j] = f2b((b * cc + a * ss) * sc);
  }
  *(u16x8*)&arr[base] = y1;
  *(u16x8*)&arr[base + 40] = y2;
}

// ---------------- causal flash attention (QBLK=256, KVBLK=64, 8 waves) -------
// q (pre-scaled), k, v: [B*H][1024][80] bf16 ; o: [B][1024][1280] bf16
// Swapped QK^T (mfma(K,Q) -> S^T): stats live per-lane (q = lr).
// K double-buffered via global_load_lds; V double-buffered transposed (Vt[d][k])
// via reg round-trip: global loads issue BEFORE QK^T, ds_writes after softmax.
__global__ __launch_bounds__(512, 4) void attn_fwd(
    const unsigned short* __restrict__ q, const unsigned short* __restrict__ k,
    const unsigned short* __restrict__ v, unsigned short* __restrict__ o) {
  __shared__ __align__(16) unsigned short Ks[2][5120];   // [64][80] linear
  __shared__ __align__(16) unsigned short Vt[2][5760];   // V^T [80][72]
  __shared__ __align__(16) unsigned short Ps[8][2304];   // per-wave [32][72]

  const int tid = threadIdx.x, lane = tid & 63, wave = tid >> 6;
  const int g = lane >> 4, lr = lane & 15;
  const int bid = blockIdx.x;
  const int t4 = bid >> 7;
  const int qi = (t4 == 0) ? 3 : (t4 == 1) ? 2 : (t4 == 2) ? 0 : 1;  // pair long+short
  const int bh = bid & 127;
  const int b = bh >> 4, h = bh & 15;
  const size_t headBase = (size_t)bh * 1024 * 80;
  const int qbase = qi * 256;
  const int wmin = qbase + wave * 32;
  const int nkv = qi * 4 + 4;
  const int vl = tid & 63, vc = tid >> 6;   // V-stage coords

  // ---- Q fragments (B-operand) in registers ----
  bf16x8 qf[2][2], qf2[2];
#pragma unroll
  for (int mf = 0; mf < 2; ++mf) {
    const unsigned short* qr = q + headBase + (size_t)(wmin + mf * 16 + lr) * 80;
    qf[mf][0] = *(const bf16x8*)(qr + g * 8);
    qf[mf][1] = *(const bf16x8*)(qr + 32 + g * 8);
    bf16x8 t = *(const bf16x8*)(qr + 64 + (g & 1) * 8);
    if (g >= 2) t = bzero8();           // zero k in [80,96)
    qf2[mf] = t;
  }

  float m_r[2] = {-INFINITY, -INFINITY}, l_r[2] = {0.f, 0.f};
  f32x4 o_acc[2][5];
#pragma unroll
  for (int mf = 0; mf < 2; ++mf)
#pragma unroll
    for (int of = 0; of < 5; ++of) o_acc[mf][of] = f32x4{0.f, 0.f, 0.f, 0.f};

  unsigned short* PsW = Ps[wave];

  // ---- prologue: stage tile 0 into buffer 0 ----
  {
    const unsigned short* vsrc = v + headBase;
    u16x8 p0 = *(const u16x8*)&vsrc[(size_t)vl * 80 + vc * 8];
    u16x8 p1;
    if (tid < 128) p1 = *(const u16x8*)&vsrc[(size_t)vl * 80 + (8 + vc) * 8];
    for (int i = tid; i < 640; i += 512)
      gload_lds16(k + headBase + i * 8, &Ks[0][i * 8]);
#pragma unroll
    for (int j = 0; j < 8; ++j) Vt[0][(vc * 8 + j) * 72 + vl] = p0[j];
    if (tid < 128) {
#pragma unroll
      for (int j = 0; j < 8; ++j) Vt[0][((8 + vc) * 8 + j) * 72 + vl] = p1[j];
    }
  }
  __syncthreads();

  for (int kv = 0; kv < nkv; ++kv) {
    const int bufI = kv & 1, nb = bufI ^ 1;
    const int kvbase = kv * 64;
    const bool doStage = (kv + 1 < nkv);
    const bool active = (kvbase <= wmin + 31);

    // ---- issue next-tile loads (V -> regs, K -> LDS async) ----
    u16x8 p0, p1;
    if (doStage) {
      const unsigned short* vsrc = v + headBase + (size_t)(kv + 1) * 5120;
      p0 = *(const u16x8*)&vsrc[(size_t)vl * 80 + vc * 8];
      if (tid < 128) p1 = *(const u16x8*)&vsrc[(size_t)vl * 80 + (8 + vc) * 8];
      const unsigned short* ksrc = k + headBase + (size_t)(kv + 1) * 5120;
      for (int i = tid; i < 640; i += 512)
        gload_lds16(ksrc + i * 8, &Ks[nb][i * 8]);
    }

    if (active) {
      const unsigned short* KsB = Ks[bufI];
      // ---- S^T = K Q^T : 24 MFMA (swapped operands) ----
      f32x4 s[2][4];
#pragma unroll
      for (int mf = 0; mf < 2; ++mf)
#pragma unroll
        for (int nf = 0; nf < 4; ++nf) s[mf][nf] = f32x4{0.f, 0.f, 0.f, 0.f};
#pragma unroll
      for (int kp = 0; kp < 2; ++kp)
#pragma unroll
        for (int nf = 0; nf < 4; ++nf) {
          bf16x8 kb = *(const bf16x8*)&KsB[(nf * 16 + lr) * 80 + kp * 32 + g * 8];
#pragma unroll
          for (int mf = 0; mf < 2; ++mf)
            s[mf][nf] = __builtin_amdgcn_mfma_f32_16x16x32_bf16(kb, qf[mf][kp],
                                                                s[mf][nf], 0, 0, 0);
        }
#pragma unroll
      for (int nf = 0; nf < 4; ++nf) {
        bf16x8 kb = *(const bf16x8*)&KsB[(nf * 16 + lr) * 80 + 64 + (g & 1) * 8];
#pragma unroll
        for (int mf = 0; mf < 2; ++mf)
          s[mf][nf] = __builtin_amdgcn_mfma_f32_16x16x32_bf16(kb, qf2[mf],
                                                              s[mf][nf], 0, 0, 0);
      }

      // ---- softmax; element (mf,nf,r): k = kvbase+nf*16+g*4+r, q = wmin+mf*16+lr
      const bool maskT = (kvbase + 63 > wmin);
      if (maskT) {
        const int kb0 = kvbase + g * 4;
        const int qq = wmin + lr;
#pragma unroll
        for (int mf = 0; mf < 2; ++mf)
#pragma unroll
          for (int nf = 0; nf < 4; ++nf)
#pragma unroll
            for (int r = 0; r < 4; ++r)
              if (kb0 + nf * 16 + r > qq + mf * 16) s[mf][nf][r] = -INFINITY;
      }
      float mt[2];
#pragma unroll
      for (int mf = 0; mf < 2; ++mf) {
        float a = fmaxf(fmaxf(s[mf][0][0], s[mf][0][1]), fmaxf(s[mf][0][2], s[mf][0][3]));
        float b2 = fmaxf(fmaxf(s[mf][1][0], s[mf][1][1]), fmaxf(s[mf][1][2], s[mf][1][3]));
        float c = fmaxf(fmaxf(s[mf][2][0], s[mf][2][1]), fmaxf(s[mf][2][2], s[mf][2][3]));
        float d = fmaxf(fmaxf(s[mf][3][0], s[mf][3][1]), fmaxf(s[mf][3][2], s[mf][3][3]));
        float m = fmaxf(fmaxf(a, b2), fmaxf(c, d));
        m = fmaxf(m, __shfl_xor(m, 16, 64));
        m = fmaxf(m, __shfl_xor(m, 32, 64));
        mt[mf] = m;
      }
      int ok = (mt[0] <= m_r[0] + 10.0f) && (mt[1] <= m_r[1] + 10.0f);
      const bool need = !__all(ok);     // defer-max (T13)
      float fr[2];
      if (need) {
#pragma unroll
        for (int mf = 0; mf < 2; ++mf) {
          float mn = fmaxf(m_r[mf], mt[mf]);
          fr[mf] = exp2f(m_r[mf] - mn);
          m_r[mf] = mn;
        }
      }
      float lt[2] = {0.f, 0.f};
#pragma unroll
      for (int mf = 0; mf < 2; ++mf)
#pragma unroll
        for (int nf = 0; nf < 4; ++nf)
#pragma unroll
          for (int r = 0; r < 4; ++r) {
            float p = exp2f(s[mf][nf][r] - m_r[mf]);
            s[mf][nf][r] = p;
            lt[mf] += p;
          }
#pragma unroll
      for (int mf = 0; mf < 2; ++mf) {
        lt[mf] += __shfl_xor(lt[mf], 16, 64);
        lt[mf] += __shfl_xor(lt[mf], 32, 64);
      }
      if (need) {
#pragma unroll
        for (int mf = 0; mf < 2; ++mf) {
          l_r[mf] = l_r[mf] * fr[mf] + lt[mf];
#pragma unroll
          for (int r = 0; r < 4; ++r) {
            float fro = __shfl(fr[mf], g * 4 + r, 64);
#pragma unroll
            for (int of = 0; of < 5; ++of) o_acc[mf][of][r] *= fro;
          }
        }
      } else {
        l_r[0] += lt[0];
        l_r[1] += lt[1];
      }

      // ---- P^T -> Ps[q][k] (integer pack: low half = even k) ----
#pragma unroll
      for (int mf = 0; mf < 2; ++mf)
#pragma unroll
        for (int nf = 0; nf < 4; ++nf) {
          unsigned w0 = (unsigned)f2b(s[mf][nf][0]) |
                        ((unsigned)f2b(s[mf][nf][1]) << 16);
          unsigned w1 = (unsigned)f2b(s[mf][nf][2]) |
                        ((unsigned)f2b(s[mf][nf][3]) << 16);
          unsigned* dst = (unsigned*)&PsW[(mf * 16 + lr) * 72 + nf * 16 + g * 4];
          dst[0] = w0;
          dst[1] = w1;
        }
    }

    // ---- write next V tile into Vt[nb] (overlaps: loads waited here) ----
    if (doStage) {
#pragma unroll
      for (int j = 0; j < 8; ++j) Vt[nb][(vc * 8 + j) * 72 + vl] = p0[j];
      if (tid < 128) {
#pragma unroll
        for (int j = 0; j < 8; ++j) Vt[nb][((8 + vc) * 8 + j) * 72 + vl] = p1[j];
      }
    }

    if (active) {
      // ---- O += P V : 20 MFMA ----
      const unsigned short* VtB = Vt[bufI];
#pragma unroll
      for (int kk = 0; kk < 2; ++kk) {
        bf16x8 pa[2];
#pragma unroll
        for (int mf = 0; mf < 2; ++mf)
          pa[mf] = *(const bf16x8*)&PsW[(mf * 16 + lr) * 72 + kk * 32 + g * 8];
#pragma unroll
        for (int of = 0; of < 5; ++of) {
          bf16x8 vv = *(const bf16x8*)&VtB[(of * 16 + lr) * 72 + kk * 32 + g * 8];
#pragma unroll
          for (int mf = 0; mf < 2; ++mf)
            o_acc[mf][of] = __builtin_amdgcn_mfma_f32_16x16x32_bf16(
                pa[mf], vv, o_acc[mf][of], 0, 0, 0);
        }
      }
    }
    __syncthreads();
  }

  // ---- epilogue: O[b][row][h*80 + d] ----
#pragma unroll
  for (int mf = 0; mf < 2; ++mf) {
    float linv = 1.0f / l_r[mf];
#pragma unroll
    for (int r = 0; r < 4; ++r) {
      float li = __shfl(linv, g * 4 + r, 64);
      int row = wmin + mf * 16 + g * 4 + r;
#pragma unroll
      for (int of = 0; of < 5; ++of)
        o[((size_t)b * 1024 + row) * 1280 + h * 80 + of * 16 + lr] =
            f2b(o_acc[mf][of][r] * li);
    }
  }
}

// ---------------- launcher ----------------
extern "C" void kernel_launch(void* const* d_in, const int* in_sizes, int n_in,
                              void* d_out, int out_size, void* d_ws, size_t ws_size,
                              hipStream_t stream) {
  const float* X     = (const float*)d_in[0];
  const float* rp    = (const float*)d_in[1];
  const float* Wqkv  = (const float*)d_in[2];
  const float* bqkv  = (const float*)d_in[3];
  const float* Wproj = (const float*)d_in[4];
  const float* bproj = (const float*)d_in[5];
  float* out = (float*)d_out;

  char* ws = (char*)d_ws;
  unsigned short* Xb     = (unsigned short*)(ws);              // 20971520 B (reused as Ob)
  unsigned short* Wqkvt  = (unsigned short*)(ws + 20971520);   // 9830400 B
  unsigned short* Wprojt = (unsigned short*)(ws + 30801920);   // 3276800 B
  float*          cosT   = (float*)(ws + 34078720);            // 163840 B
  float*          sinT   = (float*)(ws + 34242560);            // 163840 B
  unsigned short* vb     = (unsigned short*)(ws + 34406400);   // 20971520 B
  unsigned short* qb     = (unsigned short*)d_out;             // q,k live in d_out until proj
  unsigned short* kb     = qb + 10485760;
  unsigned short* Ob     = Xb;

  convert_bf16x4<<<10240, 256, 0, stream>>>(X, Xb, 2621440);
  transpose_f2b<<<dim3(120, 40), 256, 0, stream>>>(Wqkv, Wqkvt, 1280, 3840);
  transpose_f2b<<<dim3(40, 40), 256, 0, stream>>>(Wproj, Wprojt, 1280, 1280);
  rope_table<<<160, 256, 0, stream>>>(rp, cosT, sinT, 40960);
  gemm128<0><<<1920, 256, 0, stream>>>(Xb, Wqkvt, bqkv, qb, kb, vb,
                                       nullptr, 8192, 3840, 1280);
  rope_apply<<<5120, 256, 0, stream>>>(qb, kb, cosT, sinT);
  attn_fwd<<<512, 512, 0, stream>>>(qb, kb, vb, Ob);
  gemm128<1><<<640, 256, 0, stream>>>(Ob, Wprojt, bproj, nullptr,
                                      nullptr, nullptr, out, 8192, 1280, 1280);
}

// Round 5
// 349.211 us; speedup vs baseline: 1.3354x; 1.0691x over previous
//
#include <hip/hip_runtime.h>
#include <hip/hip_bf16.h>
#include <stdint.h>

#define DEV static __device__ __forceinline__

typedef __attribute__((ext_vector_type(4))) float  f32x4;
typedef __attribute__((ext_vector_type(8))) __bf16 bf16x8;
typedef __attribute__((ext_vector_type(8))) unsigned short u16x8;
typedef __attribute__((ext_vector_type(4))) unsigned short u16x4;
typedef __attribute__((ext_vector_type(4))) float  fvec4;

// scale(1/sqrt(80)) * log2(e) — folded into Q during RoPE; softmax in exp2 domain
#define SC2F 0.16129870963914802f

DEV unsigned short f2b(float f) {
  __bf16 h = (__bf16)f;
  unsigned short u; __builtin_memcpy(&u, &h, 2);
  return u;
}
DEV float b2f(unsigned short b) {
  union { unsigned int u; float f; } v; v.u = ((unsigned int)b) << 16;
  return v.f;
}
DEV bf16x8 bzero8() {
  u16x8 z = 0; bf16x8 r; __builtin_memcpy(&r, &z, 16); return r;
}

DEV void gload_lds16(const void* g, void* l) {
  __builtin_amdgcn_global_load_lds(
      (__attribute__((address_space(1))) void*)(uintptr_t)g,
      (__attribute__((address_space(3))) void*)(uintptr_t)l, 16, 0, 0);
}

// ---------------- prep kernels ----------------

__global__ void convert_bf16x4(const float* __restrict__ in,
                               unsigned short* __restrict__ out, int n4) {
  int i = blockIdx.x * 256 + threadIdx.x;
  if (i >= n4) return;
  fvec4 v = *(const fvec4*)&in[(size_t)i * 4];
  u16x4 o;
  o[0] = f2b(v[0]); o[1] = f2b(v[1]); o[2] = f2b(v[2]); o[3] = f2b(v[3]);
  *(u16x4*)&out[(size_t)i * 4] = o;
}

__global__ void transpose_f2b(const float* __restrict__ in,
                              unsigned short* __restrict__ out, int R, int C) {
  __shared__ float t[32][33];
  int c0 = blockIdx.x * 32, r0 = blockIdx.y * 32;
  int tx = threadIdx.x & 31, ty = threadIdx.x >> 5;
#pragma unroll
  for (int i = 0; i < 32; i += 8)
    t[ty + i][tx] = in[(size_t)(r0 + ty + i) * C + c0 + tx];
  __syncthreads();
#pragma unroll
  for (int i = 0; i < 32; i += 8)
    out[(size_t)(c0 + ty + i) * R + r0 + tx] = f2b(t[tx][ty + i]);
}

__global__ void rope_table(const float* __restrict__ r, float* __restrict__ c,
                           float* __restrict__ s, int n) {
  int i = blockIdx.x * 256 + threadIdx.x;
  if (i < n) { float v = r[i]; c[i] = cosf(v); s[i] = sinf(v); }
}

// ------- GEMM 256x256 tile, 8 waves, double-buffered stage-ahead (QKV) -------
// C = A(MxK) * Bt(NxK)^T; EPI 0: scatter q/k/v [B][H][L][80] bf16 + bias.
template <int EPI>
__global__ __launch_bounds__(512, 2) void gemm256(
    const unsigned short* __restrict__ A, const unsigned short* __restrict__ Bt,
    const float* __restrict__ bias,
    unsigned short* __restrict__ qo, unsigned short* __restrict__ ko,
    unsigned short* __restrict__ vo, float* __restrict__ outf,
    int M, int N, int K) {
  __shared__ __align__(16) unsigned short As[2][256 * 64];
  __shared__ __align__(16) unsigned short Bs[2][256 * 64];
  const int tid = threadIdx.x;
  const int lane = tid & 63, wave = tid >> 6;
  const int wr = wave >> 2, wc = wave & 3;          // 2 x 4 waves
  const int g = lane >> 4, lr = lane & 15;
  // bijective XCD swizzle (nwg % 8 == 0)
  const int nwg = gridDim.x, cpx = nwg >> 3;
  const int swz = (blockIdx.x & 7) * cpx + (blockIdx.x >> 3);
  const int gx = N >> 8;
  const int bx = swz % gx, by = swz / gx;
  const int m0 = by * 256, n0 = bx * 256;
  const int nt = K >> 6;

  f32x4 acc[8][4];
#pragma unroll
  for (int i = 0; i < 8; ++i)
#pragma unroll
    for (int j = 0; j < 4; ++j) acc[i][j] = f32x4{0.f, 0.f, 0.f, 0.f};

#define STAGE256(bi, t)                                                       \
  {                                                                           \
    const int k0s = (t) * 64;                                                 \
    _Pragma("unroll")                                                         \
    for (int it = 0; it < 4; ++it) {                                          \
      int e = (it * 512 + tid) * 8;                                           \
      int r = e >> 6, p = (e >> 3) & 7;                                       \
      int sc = ((p ^ (r & 7)) << 3);                                          \
      gload_lds16(&A[(size_t)(m0 + r) * K + k0s + sc], &As[bi][e]);           \
      gload_lds16(&Bt[(size_t)(n0 + r) * K + k0s + sc], &Bs[bi][e]);          \
    }                                                                         \
  }

  STAGE256(0, 0);
  __syncthreads();

  for (int t = 0; t < nt; ++t) {
    const int cur = t & 1;
    if (t + 1 < nt) STAGE256(cur ^ 1, t + 1);      // issue next tile first
#pragma unroll
    for (int kk = 0; kk < 2; ++kk) {
      bf16x8 av[8], bv[4];
#pragma unroll
      for (int mf = 0; mf < 8; ++mf) {
        int row = wr * 128 + mf * 16 + lr;
        int ch = (kk * 4 + g) ^ (row & 7);
        av[mf] = *(const bf16x8*)&As[cur][row * 64 + ch * 8];
      }
#pragma unroll
      for (int nf = 0; nf < 4; ++nf) {
        int row = wc * 64 + nf * 16 + lr;
        int ch = (kk * 4 + g) ^ (row & 7);
        bv[nf] = *(const bf16x8*)&Bs[cur][row * 64 + ch * 8];
      }
#pragma unroll
      for (int mf = 0; mf < 8; ++mf)
#pragma unroll
        for (int nf = 0; nf < 4; ++nf)
          acc[mf][nf] = __builtin_amdgcn_mfma_f32_16x16x32_bf16(
              av[mf], bv[nf], acc[mf][nf], 0, 0, 0);
    }
    __syncthreads();                                // drains stage loads once/tile
  }
#undef STAGE256

  if (EPI == 0) {
#pragma unroll
    for (int nf = 0; nf < 4; ++nf) {
      int col = n0 + wc * 64 + nf * 16 + lr;
      float bvv = bias[col];
      int s = col / 1280;
      int rem = col - s * 1280;
      int h = rem / 80, d = rem - h * 80;
      unsigned short* dst = (s == 0) ? qo : ((s == 1) ? ko : vo);
#pragma unroll
      for (int mf = 0; mf < 8; ++mf) {
#pragma unroll
        for (int r = 0; r < 4; ++r) {
          int row = m0 + wr * 128 + mf * 16 + g * 4 + r;
          int b = row >> 10, l = row & 1023;
          dst[((size_t)(b * 16 + h) * 1024 + l) * 80 + d] =
              f2b(acc[mf][nf][r] + bvv);
        }
      }
    }
  } else {
#pragma unroll
    for (int mf = 0; mf < 8; ++mf) {
#pragma unroll
      for (int r = 0; r < 4; ++r) {
        int row = m0 + wr * 128 + mf * 16 + g * 4 + r;
#pragma unroll
        for (int nf = 0; nf < 4; ++nf) {
          int col = n0 + wc * 64 + nf * 16 + lr;
          outf[(size_t)row * N + col] = acc[mf][nf][r] + bias[col];
        }
      }
    }
  }
}

// ---------------- GEMM 128x128 (proj) ----------------
template <int EPI>
__global__ __launch_bounds__(256) void gemm128(
    const unsigned short* __restrict__ A, const unsigned short* __restrict__ Bt,
    const float* __restrict__ bias,
    unsigned short* __restrict__ qo, unsigned short* __restrict__ ko,
    unsigned short* __restrict__ vo, float* __restrict__ outf,
    int M, int N, int K) {
  __shared__ __align__(16) unsigned short As[128 * 64];
  __shared__ __align__(16) unsigned short Bs[128 * 64];
  const int tid = threadIdx.x;
  const int lane = tid & 63, wave = tid >> 6;
  const int wr = wave >> 1, wc = wave & 1;
  const int g = lane >> 4, lr = lane & 15;
  const int nwg = gridDim.x, cpx = nwg >> 3;
  const int swz = (blockIdx.x & 7) * cpx + (blockIdx.x >> 3);
  const int gx = N >> 7;
  const int bx = swz % gx, by = swz / gx;
  const int m0 = by * 128, n0 = bx * 128;

  f32x4 acc[4][4];
#pragma unroll
  for (int i = 0; i < 4; ++i)
#pragma unroll
    for (int j = 0; j < 4; ++j) acc[i][j] = f32x4{0.f, 0.f, 0.f, 0.f};

  for (int k0 = 0; k0 < K; k0 += 64) {
#pragma unroll
    for (int it = 0; it < 4; ++it) {
      int e = (it * 256 + tid) * 8;
      int r = e >> 6, p = (e >> 3) & 7;
      int sc = ((p ^ (r & 7)) << 3);
      gload_lds16(&A[(size_t)(m0 + r) * K + k0 + sc], &As[e]);
      gload_lds16(&Bt[(size_t)(n0 + r) * K + k0 + sc], &Bs[e]);
    }
    __syncthreads();
#pragma unroll
    for (int kk = 0; kk < 2; ++kk) {
      bf16x8 av[4], bv[4];
#pragma unroll
      for (int mf = 0; mf < 4; ++mf) {
        int row = wr * 64 + mf * 16 + lr;
        int ch = (kk * 4 + g) ^ (row & 7);
        av[mf] = *(const bf16x8*)&As[row * 64 + ch * 8];
      }
#pragma unroll
      for (int nf = 0; nf < 4; ++nf) {
        int row = wc * 64 + nf * 16 + lr;
        int ch = (kk * 4 + g) ^ (row & 7);
        bv[nf] = *(const bf16x8*)&Bs[row * 64 + ch * 8];
      }
#pragma unroll
      for (int mf = 0; mf < 4; ++mf)
#pragma unroll
        for (int nf = 0; nf < 4; ++nf)
          acc[mf][nf] = __builtin_amdgcn_mfma_f32_16x16x32_bf16(
              av[mf], bv[nf], acc[mf][nf], 0, 0, 0);
    }
    __syncthreads();
  }

  if (EPI == 0) {
#pragma unroll
    for (int nf = 0; nf < 4; ++nf) {
      int col = n0 + wc * 64 + nf * 16 + lr;
      float bvv = bias[col];
      int s = col / 1280;
      int rem = col - s * 1280;
      int h = rem / 80, d = rem - h * 80;
      unsigned short* dst = (s == 0) ? qo : ((s == 1) ? ko : vo);
#pragma unroll
      for (int mf = 0; mf < 4; ++mf) {
#pragma unroll
        for (int r = 0; r < 4; ++r) {
          int row = m0 + wr * 64 + mf * 16 + g * 4 + r;
          int b = row >> 10, l = row & 1023;
          dst[((size_t)(b * 16 + h) * 1024 + l) * 80 + d] =
              f2b(acc[mf][nf][r] + bvv);
        }
      }
    }
  } else {
#pragma unroll
    for (int mf = 0; mf < 4; ++mf) {
#pragma unroll
      for (int r = 0; r < 4; ++r) {
        int row = m0 + wr * 64 + mf * 16 + g * 4 + r;
#pragma unroll
        for (int nf = 0; nf < 4; ++nf) {
          int col = n0 + wc * 64 + nf * 16 + lr;
          outf[(size_t)row * N + col] = acc[mf][nf][r] + bias[col];
        }
      }
    }
  }
}

// ---------------- RoPE in place; q additionally scaled by SC2F ----------------
__global__ void rope_apply(unsigned short* __restrict__ q0,
                           unsigned short* __restrict__ q1,
                           const float* __restrict__ cosT,
                           const float* __restrict__ sinT) {
  int i = blockIdx.x * 256 + threadIdx.x;
  if (i >= 2 * 131072 * 5) return;
  bool isq = (i < 131072 * 5);
  unsigned short* arr = isq ? q0 : q1;
  float sc = isq ? SC2F : 1.0f;
  int rem = isq ? i : (i - 131072 * 5);
  int row = rem / 5, c = rem - (rem / 5) * 5;
  int l = row & 1023;
  size_t base = (size_t)row * 80 + c * 8;
  u16x8 x1 = *(const u16x8*)&arr[base];
  u16x8 x2 = *(const u16x8*)&arr[base + 40];
  const float* cp = &cosT[l * 40 + c * 8];
  const float* sp = &sinT[l * 40 + c * 8];
  u16x8 y1, y2;
#pragma unroll
  for (int j = 0; j < 8; ++j) {
    float a = b2f(x1[j]), b = b2f(x2[j]);
    float cc = cp[j], ss = sp[j];
    y1[j] = f2b((a * cc - b * ss) * sc);
    y2[j] = f2b((b * cc + a * ss) * sc);
  }
  *(u16x8*)&arr[base] = y1;
  *(u16x8*)&arr[base + 40] = y2;
}

// ---------------- causal flash attention (QBLK=256, KVBLK=64, 8 waves) -------
__global__ __launch_bounds__(512, 4) void attn_fwd(
    const unsigned short* __restrict__ q, const unsigned short* __restrict__ k,
    const unsigned short* __restrict__ v, unsigned short* __restrict__ o) {
  __shared__ __align__(16) unsigned short Ks[2][5120];   // [64][80] linear
  __shared__ __align__(16) unsigned short Vt[2][5760];   // V^T [80][72]
  __shared__ __align__(16) unsigned short Ps[8][2304];   // per-wave [32][72]

  const int tid = threadIdx.x, lane = tid & 63, wave = tid >> 6;
  const int g = lane >> 4, lr = lane & 15;
  const int bid = blockIdx.x;
  const int t4 = bid >> 7;
  const int qi = (t4 == 0) ? 3 : (t4 == 1) ? 2 : (t4 == 2) ? 0 : 1;  // pair long+short
  const int bh = bid & 127;
  const int b = bh >> 4, h = bh & 15;
  const size_t headBase = (size_t)bh * 1024 * 80;
  const int qbase = qi * 256;
  const int wmin = qbase + wave * 32;
  const int nkv = qi * 4 + 4;
  const int vl = tid & 63, vc = tid >> 6;   // V-stage coords

  // ---- Q fragments (B-operand) in registers ----
  bf16x8 qf[2][2], qf2[2];
#pragma unroll
  for (int mf = 0; mf < 2; ++mf) {
    const unsigned short* qr = q + headBase + (size_t)(wmin + mf * 16 + lr) * 80;
    qf[mf][0] = *(const bf16x8*)(qr + g * 8);
    qf[mf][1] = *(const bf16x8*)(qr + 32 + g * 8);
    bf16x8 t = *(const bf16x8*)(qr + 64 + (g & 1) * 8);
    if (g >= 2) t = bzero8();           // zero k in [80,96)
    qf2[mf] = t;
  }

  float m_r[2] = {-INFINITY, -INFINITY}, l_r[2] = {0.f, 0.f};
  f32x4 o_acc[2][5];
#pragma unroll
  for (int mf = 0; mf < 2; ++mf)
#pragma unroll
    for (int of = 0; of < 5; ++of) o_acc[mf][of] = f32x4{0.f, 0.f, 0.f, 0.f};

  unsigned short* PsW = Ps[wave];

  // ---- prologue: stage tile 0 into buffer 0 ----
  {
    const unsigned short* vsrc = v + headBase;
    u16x8 p0 = *(const u16x8*)&vsrc[(size_t)vl * 80 + vc * 8];
    u16x8 p1;
    if (tid < 128) p1 = *(const u16x8*)&vsrc[(size_t)vl * 80 + (8 + vc) * 8];
    for (int i = tid; i < 640; i += 512)
      gload_lds16(k + headBase + i * 8, &Ks[0][i * 8]);
#pragma unroll
    for (int j = 0; j < 8; ++j) Vt[0][(vc * 8 + j) * 72 + vl] = p0[j];
    if (tid < 128) {
#pragma unroll
      for (int j = 0; j < 8; ++j) Vt[0][((8 + vc) * 8 + j) * 72 + vl] = p1[j];
    }
  }
  __syncthreads();

  for (int kv = 0; kv < nkv; ++kv) {
    const int bufI = kv & 1, nb = bufI ^ 1;
    const int kvbase = kv * 64;
    const bool doStage = (kv + 1 < nkv);
    const bool active = (kvbase <= wmin + 31);

    // ---- issue next-tile loads (V -> regs, K -> LDS async) ----
    u16x8 p0, p1;
    if (doStage) {
      const unsigned short* vsrc = v + headBase + (size_t)(kv + 1) * 5120;
      p0 = *(const u16x8*)&vsrc[(size_t)vl * 80 + vc * 8];
      if (tid < 128) p1 = *(const u16x8*)&vsrc[(size_t)vl * 80 + (8 + vc) * 8];
      const unsigned short* ksrc = k + headBase + (size_t)(kv + 1) * 5120;
      for (int i = tid; i < 640; i += 512)
        gload_lds16(ksrc + i * 8, &Ks[nb][i * 8]);
    }

    if (active) {
      const unsigned short* KsB = Ks[bufI];
      // ---- S^T = K Q^T : 24 MFMA (swapped operands) ----
      f32x4 s[2][4];
#pragma unroll
      for (int mf = 0; mf < 2; ++mf)
#pragma unroll
        for (int nf = 0; nf < 4; ++nf) s[mf][nf] = f32x4{0.f, 0.f, 0.f, 0.f};
#pragma unroll
      for (int kp = 0; kp < 2; ++kp)
#pragma unroll
        for (int nf = 0; nf < 4; ++nf) {
          bf16x8 kb = *(const bf16x8*)&KsB[(nf * 16 + lr) * 80 + kp * 32 + g * 8];
#pragma unroll
          for (int mf = 0; mf < 2; ++mf)
            s[mf][nf] = __builtin_amdgcn_mfma_f32_16x16x32_bf16(kb, qf[mf][kp],
                                                                s[mf][nf], 0, 0, 0);
        }
#pragma unroll
      for (int nf = 0; nf < 4; ++nf) {
        bf16x8 kb = *(const bf16x8*)&KsB[(nf * 16 + lr) * 80 + 64 + (g & 1) * 8];
#pragma unroll
        for (int mf = 0; mf < 2; ++mf)
          s[mf][nf] = __builtin_amdgcn_mfma_f32_16x16x32_bf16(kb, qf2[mf],
                                                              s[mf][nf], 0, 0, 0);
      }

      // ---- softmax; element (mf,nf,r): k = kvbase+nf*16+g*4+r, q = wmin+mf*16+lr
      const bool maskT = (kvbase + 63 > wmin);
      if (maskT) {
        const int kb0 = kvbase + g * 4;
        const int qq = wmin + lr;
#pragma unroll
        for (int mf = 0; mf < 2; ++mf)
#pragma unroll
          for (int nf = 0; nf < 4; ++nf)
#pragma unroll
            for (int r = 0; r < 4; ++r)
              if (kb0 + nf * 16 + r > qq + mf * 16) s[mf][nf][r] = -INFINITY;
      }
      float mt[2];
#pragma unroll
      for (int mf = 0; mf < 2; ++mf) {
        float a = fmaxf(fmaxf(s[mf][0][0], s[mf][0][1]), fmaxf(s[mf][0][2], s[mf][0][3]));
        float b2 = fmaxf(fmaxf(s[mf][1][0], s[mf][1][1]), fmaxf(s[mf][1][2], s[mf][1][3]));
        float c = fmaxf(fmaxf(s[mf][2][0], s[mf][2][1]), fmaxf(s[mf][2][2], s[mf][2][3]));
        float d = fmaxf(fmaxf(s[mf][3][0], s[mf][3][1]), fmaxf(s[mf][3][2], s[mf][3][3]));
        float m = fmaxf(fmaxf(a, b2), fmaxf(c, d));
        m = fmaxf(m, __shfl_xor(m, 16, 64));
        m = fmaxf(m, __shfl_xor(m, 32, 64));
        mt[mf] = m;
      }
      int ok = (mt[0] <= m_r[0] + 10.0f) && (mt[1] <= m_r[1] + 10.0f);
      const bool need = !__all(ok);     // defer-max (T13)
      float fr[2];
      if (need) {
#pragma unroll
        for (int mf = 0; mf < 2; ++mf) {
          float mn = fmaxf(m_r[mf], mt[mf]);
          fr[mf] = exp2f(m_r[mf] - mn);
          m_r[mf] = mn;
        }
      }
      float lt[2] = {0.f, 0.f};
#pragma unroll
      for (int mf = 0; mf < 2; ++mf)
#pragma unroll
        for (int nf = 0; nf < 4; ++nf)
#pragma unroll
          for (int r = 0; r < 4; ++r) {
            float p = exp2f(s[mf][nf][r] - m_r[mf]);
            s[mf][nf][r] = p;
            lt[mf] += p;
          }
#pragma unroll
      for (int mf = 0; mf < 2; ++mf) {
        lt[mf] += __shfl_xor(lt[mf], 16, 64);
        lt[mf] += __shfl_xor(lt[mf], 32, 64);
      }
      if (need) {
#pragma unroll
        for (int mf = 0; mf < 2; ++mf) {
          l_r[mf] = l_r[mf] * fr[mf] + lt[mf];
#pragma unroll
          for (int r = 0; r < 4; ++r) {
            float fro = __shfl(fr[mf], g * 4 + r, 64);
#pragma unroll
            for (int of = 0; of < 5; ++of) o_acc[mf][of][r] *= fro;
          }
        }
      } else {
        l_r[0] += lt[0];
        l_r[1] += lt[1];
      }

      // ---- P^T -> Ps[q][k] (integer pack: low half = even k) ----
#pragma unroll
      for (int mf = 0; mf < 2; ++mf)
#pragma unroll
        for (int nf = 0; nf < 4; ++nf) {
          unsigned w0 = (unsigned)f2b(s[mf][nf][0]) |
                        ((unsigned)f2b(s[mf][nf][1]) << 16);
          unsigned w1 = (unsigned)f2b(s[mf][nf][2]) |
                        ((unsigned)f2b(s[mf][nf][3]) << 16);
          unsigned* dst = (unsigned*)&PsW[(mf * 16 + lr) * 72 + nf * 16 + g * 4];
          dst[0] = w0;
          dst[1] = w1;
        }
    }

    // ---- write next V tile into Vt[nb] (overlaps: loads waited here) ----
    if (doStage) {
#pragma unroll
      for (int j = 0; j < 8; ++j) Vt[nb][(vc * 8 + j) * 72 + vl] = p0[j];
      if (tid < 128) {
#pragma unroll
        for (int j = 0; j < 8; ++j) Vt[nb][((8 + vc) * 8 + j) * 72 + vl] = p1[j];
      }
    }

    if (active) {
      // ---- O += P V : 20 MFMA ----
      const unsigned short* VtB = Vt[bufI];
#pragma unroll
      for (int kk = 0; kk < 2; ++kk) {
        bf16x8 pa[2];
#pragma unroll
        for (int mf = 0; mf < 2; ++mf)
          pa[mf] = *(const bf16x8*)&PsW[(mf * 16 + lr) * 72 + kk * 32 + g * 8];
#pragma unroll
        for (int of = 0; of < 5; ++of) {
          bf16x8 vv = *(const bf16x8*)&VtB[(of * 16 + lr) * 72 + kk * 32 + g * 8];
#pragma unroll
          for (int mf = 0; mf < 2; ++mf)
            o_acc[mf][of] = __builtin_amdgcn_mfma_f32_16x16x32_bf16(
                pa[mf], vv, o_acc[mf][of], 0, 0, 0);
        }
      }
    }
    __syncthreads();
  }

  // ---- epilogue: O[b][row][h*80 + d] ----
#pragma unroll
  for (int mf = 0; mf < 2; ++mf) {
    float linv = 1.0f / l_r[mf];
#pragma unroll
    for (int r = 0; r < 4; ++r) {
      float li = __shfl(linv, g * 4 + r, 64);
      int row = wmin + mf * 16 + g * 4 + r;
#pragma unroll
      for (int of = 0; of < 5; ++of)
        o[((size_t)b * 1024 + row) * 1280 + h * 80 + of * 16 + lr] =
            f2b(o_acc[mf][of][r] * li);
    }
  }
}

// ---------------- launcher ----------------
extern "C" void kernel_launch(void* const* d_in, const int* in_sizes, int n_in,
                              void* d_out, int out_size, void* d_ws, size_t ws_size,
                              hipStream_t stream) {
  const float* X     = (const float*)d_in[0];
  const float* rp    = (const float*)d_in[1];
  const float* Wqkv  = (const float*)d_in[2];
  const float* bqkv  = (const float*)d_in[3];
  const float* Wproj = (const float*)d_in[4];
  const float* bproj = (const float*)d_in[5];
  float* out = (float*)d_out;

  char* ws = (char*)d_ws;
  unsigned short* Xb     = (unsigned short*)(ws);              // 20971520 B (reused as Ob)
  unsigned short* Wqkvt  = (unsigned short*)(ws + 20971520);   // 9830400 B
  unsigned short* Wprojt = (unsigned short*)(ws + 30801920);   // 3276800 B
  float*          cosT   = (float*)(ws + 34078720);            // 163840 B
  float*          sinT   = (float*)(ws + 34242560);            // 163840 B
  unsigned short* vb     = (unsigned short*)(ws + 34406400);   // 20971520 B
  unsigned short* qb     = (unsigned short*)d_out;             // q,k live in d_out until proj
  unsigned short* kb     = qb + 10485760;
  unsigned short* Ob     = Xb;

  convert_bf16x4<<<10240, 256, 0, stream>>>(X, Xb, 2621440);
  transpose_f2b<<<dim3(120, 40), 256, 0, stream>>>(Wqkv, Wqkvt, 1280, 3840);
  transpose_f2b<<<dim3(40, 40), 256, 0, stream>>>(Wproj, Wprojt, 1280, 1280);
  rope_table<<<160, 256, 0, stream>>>(rp, cosT, sinT, 40960);
  gemm256<0><<<480, 512, 0, stream>>>(Xb, Wqkvt, bqkv, qb, kb, vb,
                                      nullptr, 8192, 3840, 1280);
  rope_apply<<<5120, 256, 0, stream>>>(qb, kb, cosT, sinT);
  attn_fwd<<<512, 512, 0, stream>>>(qb, kb, vb, Ob);
  gemm128<1><<<640, 256, 0, stream>>>(Ob, Wprojt, bproj, nullptr,
                                      nullptr, nullptr, out, 8192, 1280, 1280);
}

// Round 6
// 329.911 us; speedup vs baseline: 1.4135x; 1.0585x over previous
//
#include <hip/hip_runtime.h>
#include <hip/hip_bf16.h>
#include <stdint.h>

#define DEV static __device__ __forceinline__

typedef __attribute__((ext_vector_type(4))) float  f32x4;
typedef __attribute__((ext_vector_type(8))) __bf16 bf16x8;
typedef __attribute__((ext_vector_type(8))) unsigned short u16x8;
typedef __attribute__((ext_vector_type(4))) unsigned short u16x4;
typedef __attribute__((ext_vector_type(4))) float  fvec4;

// scale(1/sqrt(80)) * log2(e) — folded into Q during RoPE; softmax in exp2 domain
#define SC2F 0.16129870963914802f

DEV unsigned short f2b(float f) {
  __bf16 h = (__bf16)f;
  unsigned short u; __builtin_memcpy(&u, &h, 2);
  return u;
}
DEV float b2f(unsigned short b) {
  union { unsigned int u; float f; } v; v.u = ((unsigned int)b) << 16;
  return v.f;
}
DEV bf16x8 bzero8() {
  u16x8 z = 0; bf16x8 r; __builtin_memcpy(&r, &z, 16); return r;
}

DEV void gload_lds16(const void* g, void* l) {
  __builtin_amdgcn_global_load_lds(
      (__attribute__((address_space(1))) void*)(uintptr_t)g,
      (__attribute__((address_space(3))) void*)(uintptr_t)l, 16, 0, 0);
}

// ---------------- prep kernels ----------------

__global__ void convert_bf16x4(const float* __restrict__ in,
                               unsigned short* __restrict__ out, int n4) {
  int i = blockIdx.x * 256 + threadIdx.x;
  if (i >= n4) return;
  fvec4 v = *(const fvec4*)&in[(size_t)i * 4];
  u16x4 o;
  o[0] = f2b(v[0]); o[1] = f2b(v[1]); o[2] = f2b(v[2]); o[3] = f2b(v[3]);
  *(u16x4*)&out[(size_t)i * 4] = o;
}

__global__ void transpose_f2b(const float* __restrict__ in,
                              unsigned short* __restrict__ out, int R, int C) {
  __shared__ float t[32][33];
  int c0 = blockIdx.x * 32, r0 = blockIdx.y * 32;
  int tx = threadIdx.x & 31, ty = threadIdx.x >> 5;
#pragma unroll
  for (int i = 0; i < 32; i += 8)
    t[ty + i][tx] = in[(size_t)(r0 + ty + i) * C + c0 + tx];
  __syncthreads();
#pragma unroll
  for (int i = 0; i < 32; i += 8)
    out[(size_t)(c0 + ty + i) * R + r0 + tx] = f2b(t[tx][ty + i]);
}

__global__ void rope_table(const float* __restrict__ r, float* __restrict__ c,
                           float* __restrict__ s, int n) {
  int i = blockIdx.x * 256 + threadIdx.x;
  if (i < n) { float v = r[i]; c[i] = cosf(v); s[i] = sinf(v); }
}

// ------- GEMM 256x256 tile, 8 waves, double-buffered stage-ahead (QKV) -------
// C = A(MxK) * Bt(NxK)^T; EPI 0: scatter q/k [B][H][L][80] bf16 + bias,
//                         v TRANSPOSED per head: vo[(bh*80+d)*1024 + l].
template <int EPI>
__global__ __launch_bounds__(512, 2) void gemm256(
    const unsigned short* __restrict__ A, const unsigned short* __restrict__ Bt,
    const float* __restrict__ bias,
    unsigned short* __restrict__ qo, unsigned short* __restrict__ ko,
    unsigned short* __restrict__ vo, float* __restrict__ outf,
    int M, int N, int K) {
  __shared__ __align__(16) unsigned short As[2][256 * 64];
  __shared__ __align__(16) unsigned short Bs[2][256 * 64];
  const int tid = threadIdx.x;
  const int lane = tid & 63, wave = tid >> 6;
  const int wr = wave >> 2, wc = wave & 3;          // 2 x 4 waves
  const int g = lane >> 4, lr = lane & 15;
  // bijective XCD swizzle (nwg % 8 == 0)
  const int nwg = gridDim.x, cpx = nwg >> 3;
  const int swz = (blockIdx.x & 7) * cpx + (blockIdx.x >> 3);
  const int gx = N >> 8;
  const int bx = swz % gx, by = swz / gx;
  const int m0 = by * 256, n0 = bx * 256;
  const int nt = K >> 6;

  f32x4 acc[8][4];
#pragma unroll
  for (int i = 0; i < 8; ++i)
#pragma unroll
    for (int j = 0; j < 4; ++j) acc[i][j] = f32x4{0.f, 0.f, 0.f, 0.f};

#define STAGE256(bi, t)                                                       \
  {                                                                           \
    const int k0s = (t) * 64;                                                 \
    _Pragma("unroll")                                                         \
    for (int it = 0; it < 4; ++it) {                                          \
      int e = (it * 512 + tid) * 8;                                           \
      int r = e >> 6, p = (e >> 3) & 7;                                       \
      int sc = ((p ^ (r & 7)) << 3);                                          \
      gload_lds16(&A[(size_t)(m0 + r) * K + k0s + sc], &As[bi][e]);           \
      gload_lds16(&Bt[(size_t)(n0 + r) * K + k0s + sc], &Bs[bi][e]);          \
    }                                                                         \
  }

  STAGE256(0, 0);
  __syncthreads();

  for (int t = 0; t < nt; ++t) {
    const int cur = t & 1;
    if (t + 1 < nt) STAGE256(cur ^ 1, t + 1);      // issue next tile first
#pragma unroll
    for (int kk = 0; kk < 2; ++kk) {
      bf16x8 av[8], bv[4];
#pragma unroll
      for (int mf = 0; mf < 8; ++mf) {
        int row = wr * 128 + mf * 16 + lr;
        int ch = (kk * 4 + g) ^ (row & 7);
        av[mf] = *(const bf16x8*)&As[cur][row * 64 + ch * 8];
      }
#pragma unroll
      for (int nf = 0; nf < 4; ++nf) {
        int row = wc * 64 + nf * 16 + lr;
        int ch = (kk * 4 + g) ^ (row & 7);
        bv[nf] = *(const bf16x8*)&Bs[cur][row * 64 + ch * 8];
      }
#pragma unroll
      for (int mf = 0; mf < 8; ++mf)
#pragma unroll
        for (int nf = 0; nf < 4; ++nf)
          acc[mf][nf] = __builtin_amdgcn_mfma_f32_16x16x32_bf16(
              av[mf], bv[nf], acc[mf][nf], 0, 0, 0);
    }
    __syncthreads();                                // drains stage loads once/tile
  }
#undef STAGE256

  if (EPI == 0) {
#pragma unroll
    for (int nf = 0; nf < 4; ++nf) {
      int col = n0 + wc * 64 + nf * 16 + lr;
      float bvv = bias[col];
      int s = col / 1280;
      int rem = col - s * 1280;
      int h = rem / 80, d = rem - h * 80;
      if (s == 2) {
#pragma unroll
        for (int mf = 0; mf < 8; ++mf) {
#pragma unroll
          for (int r = 0; r < 4; ++r) {
            int row = m0 + wr * 128 + mf * 16 + g * 4 + r;
            int b = row >> 10, l = row & 1023;
            vo[((size_t)((b * 16 + h) * 80) + d) * 1024 + l] =
                f2b(acc[mf][nf][r] + bvv);
          }
        }
      } else {
        unsigned short* dst = (s == 0) ? qo : ko;
#pragma unroll
        for (int mf = 0; mf < 8; ++mf) {
#pragma unroll
          for (int r = 0; r < 4; ++r) {
            int row = m0 + wr * 128 + mf * 16 + g * 4 + r;
            int b = row >> 10, l = row & 1023;
            dst[((size_t)(b * 16 + h) * 1024 + l) * 80 + d] =
                f2b(acc[mf][nf][r] + bvv);
          }
        }
      }
    }
  } else {
#pragma unroll
    for (int mf = 0; mf < 8; ++mf) {
#pragma unroll
      for (int r = 0; r < 4; ++r) {
        int row = m0 + wr * 128 + mf * 16 + g * 4 + r;
#pragma unroll
        for (int nf = 0; nf < 4; ++nf) {
          int col = n0 + wc * 64 + nf * 16 + lr;
          outf[(size_t)row * N + col] = acc[mf][nf][r] + bias[col];
        }
      }
    }
  }
}

// ---------------- GEMM 128x128 (proj) ----------------
template <int EPI>
__global__ __launch_bounds__(256) void gemm128(
    const unsigned short* __restrict__ A, const unsigned short* __restrict__ Bt,
    const float* __restrict__ bias, float* __restrict__ outf,
    int M, int N, int K) {
  __shared__ __align__(16) unsigned short As[128 * 64];
  __shared__ __align__(16) unsigned short Bs[128 * 64];
  const int tid = threadIdx.x;
  const int lane = tid & 63, wave = tid >> 6;
  const int wr = wave >> 1, wc = wave & 1;
  const int g = lane >> 4, lr = lane & 15;
  const int nwg = gridDim.x, cpx = nwg >> 3;
  const int swz = (blockIdx.x & 7) * cpx + (blockIdx.x >> 3);
  const int gx = N >> 7;
  const int bx = swz % gx, by = swz / gx;
  const int m0 = by * 128, n0 = bx * 128;

  f32x4 acc[4][4];
#pragma unroll
  for (int i = 0; i < 4; ++i)
#pragma unroll
    for (int j = 0; j < 4; ++j) acc[i][j] = f32x4{0.f, 0.f, 0.f, 0.f};

  for (int k0 = 0; k0 < K; k0 += 64) {
#pragma unroll
    for (int it = 0; it < 4; ++it) {
      int e = (it * 256 + tid) * 8;
      int r = e >> 6, p = (e >> 3) & 7;
      int sc = ((p ^ (r & 7)) << 3);
      gload_lds16(&A[(size_t)(m0 + r) * K + k0 + sc], &As[e]);
      gload_lds16(&Bt[(size_t)(n0 + r) * K + k0 + sc], &Bs[e]);
    }
    __syncthreads();
#pragma unroll
    for (int kk = 0; kk < 2; ++kk) {
      bf16x8 av[4], bv[4];
#pragma unroll
      for (int mf = 0; mf < 4; ++mf) {
        int row = wr * 64 + mf * 16 + lr;
        int ch = (kk * 4 + g) ^ (row & 7);
        av[mf] = *(const bf16x8*)&As[row * 64 + ch * 8];
      }
#pragma unroll
      for (int nf = 0; nf < 4; ++nf) {
        int row = wc * 64 + nf * 16 + lr;
        int ch = (kk * 4 + g) ^ (row & 7);
        bv[nf] = *(const bf16x8*)&Bs[row * 64 + ch * 8];
      }
#pragma unroll
      for (int mf = 0; mf < 4; ++mf)
#pragma unroll
        for (int nf = 0; nf < 4; ++nf)
          acc[mf][nf] = __builtin_amdgcn_mfma_f32_16x16x32_bf16(
              av[mf], bv[nf], acc[mf][nf], 0, 0, 0);
    }
    __syncthreads();
  }

#pragma unroll
  for (int mf = 0; mf < 4; ++mf) {
#pragma unroll
    for (int r = 0; r < 4; ++r) {
      int row = m0 + wr * 64 + mf * 16 + g * 4 + r;
#pragma unroll
      for (int nf = 0; nf < 4; ++nf) {
        int col = n0 + wc * 64 + nf * 16 + lr;
        outf[(size_t)row * N + col] = acc[mf][nf][r] + bias[col];
      }
    }
  }
}

// ---------------- RoPE in place; q additionally scaled by SC2F ----------------
__global__ void rope_apply(unsigned short* __restrict__ q0,
                           unsigned short* __restrict__ q1,
                           const float* __restrict__ cosT,
                           const float* __restrict__ sinT) {
  int i = blockIdx.x * 256 + threadIdx.x;
  if (i >= 2 * 131072 * 5) return;
  bool isq = (i < 131072 * 5);
  unsigned short* arr = isq ? q0 : q1;
  float sc = isq ? SC2F : 1.0f;
  int rem = isq ? i : (i - 131072 * 5);
  int row = rem / 5, c = rem - (rem / 5) * 5;
  int l = row & 1023;
  size_t base = (size_t)row * 80 + c * 8;
  u16x8 x1 = *(const u16x8*)&arr[base];
  u16x8 x2 = *(const u16x8*)&arr[base + 40];
  const float* cp = &cosT[l * 40 + c * 8];
  const float* sp = &sinT[l * 40 + c * 8];
  u16x8 y1, y2;
#pragma unroll
  for (int j = 0; j < 8; ++j) {
    float a = b2f(x1[j]), b = b2f(x2[j]);
    float cc = cp[j], ss = sp[j];
    y1[j] = f2b((a * cc - b * ss) * sc);
    y2[j] = f2b((b * cc + a * ss) * sc);
  }
  *(u16x8*)&arr[base] = y1;
  *(u16x8*)&arr[base + 40] = y2;
}

// ---------------- causal flash attention (QBLK=256, KVBLK=64, 8 waves) -------
// q (pre-scaled), k: [B*H][1024][80] bf16 ; vt: [B*H][80][1024] bf16 (V^T)
// o: [B][1024][1280] bf16.  All K/V staging is pure async global_load_lds.
__global__ __launch_bounds__(512, 4) void attn_fwd(
    const unsigned short* __restrict__ q, const unsigned short* __restrict__ k,
    const unsigned short* __restrict__ vt, unsigned short* __restrict__ o) {
  __shared__ __align__(16) unsigned short Ks[2][5120];   // [64][80] linear
  __shared__ __align__(16) unsigned short Vt[2][5760];   // V^T [80][72]
  __shared__ __align__(16) unsigned short Ps[8][2304];   // per-wave [32][72]

  const int tid = threadIdx.x, lane = tid & 63, wave = tid >> 6;
  const int g = lane >> 4, lr = lane & 15;
  const int bid = blockIdx.x;
  const int t4 = bid >> 7;
  const int qi = (t4 == 0) ? 3 : (t4 == 1) ? 2 : (t4 == 2) ? 0 : 1;  // pair long+short
  const int bh = bid & 127;
  const int b = bh >> 4, h = bh & 15;
  const size_t headBase = (size_t)bh * 1024 * 80;        // q,k
  const size_t vHeadBase = (size_t)bh * 80 * 1024;       // vt
  const int qbase = qi * 256;
  const int wmin = qbase + wave * 32;
  const int nkv = qi * 4 + 4;

  // thread-constant V^T staging coords: chunk c -> row c/9, col c%9 (col 8 = pad)
  const int vr0 = tid / 9, vcol0 = tid - vr0 * 9;
  const int vt2 = tid + 512;
  const int vr1 = vt2 / 9, vcol1 = vt2 - vr1 * 9;        // valid if tid < 208
  const int voff0 = vr0 * 1024 + (vcol0 < 8 ? vcol0 * 8 : 56);
  const int voff1 = vr1 * 1024 + (vcol1 < 8 ? vcol1 * 8 : 56);

  // ---- Q fragments (B-operand) in registers ----
  bf16x8 qf[2][2], qf2[2];
#pragma unroll
  for (int mf = 0; mf < 2; ++mf) {
    const unsigned short* qr = q + headBase + (size_t)(wmin + mf * 16 + lr) * 80;
    qf[mf][0] = *(const bf16x8*)(qr + g * 8);
    qf[mf][1] = *(const bf16x8*)(qr + 32 + g * 8);
    bf16x8 t = *(const bf16x8*)(qr + 64 + (g & 1) * 8);
    if (g >= 2) t = bzero8();           // zero k in [80,96)
    qf2[mf] = t;
  }

  float m_r[2] = {-INFINITY, -INFINITY}, l_r[2] = {0.f, 0.f};
  f32x4 o_acc[2][5];
#pragma unroll
  for (int mf = 0; mf < 2; ++mf)
#pragma unroll
    for (int of = 0; of < 5; ++of) o_acc[mf][of] = f32x4{0.f, 0.f, 0.f, 0.f};

  unsigned short* PsW = Ps[wave];

#define STAGE_KV(kvb, bi)                                                     \
  {                                                                           \
    const unsigned short* ksrc = k + headBase + (size_t)(kvb) * 80;           \
    for (int i = tid; i < 640; i += 512)                                      \
      gload_lds16(ksrc + i * 8, &Ks[bi][i * 8]);                              \
    const unsigned short* vsrc = vt + vHeadBase + (kvb);                      \
    gload_lds16(vsrc + voff0, &Vt[bi][tid * 8]);                              \
    if (tid < 208) gload_lds16(vsrc + voff1, &Vt[bi][vt2 * 8]);               \
  }

  STAGE_KV(0, 0);
  __syncthreads();

  for (int kv = 0; kv < nkv; ++kv) {
    const int bufI = kv & 1, nb = bufI ^ 1;
    const int kvbase = kv * 64;
    if (kv + 1 < nkv) STAGE_KV((kv + 1) * 64, nb);   // async, drained at barrier

    if (kvbase <= wmin + 31) {
      const unsigned short* KsB = Ks[bufI];
      // ---- S^T = K Q^T : 24 MFMA (swapped operands) ----
      f32x4 s[2][4];
#pragma unroll
      for (int mf = 0; mf < 2; ++mf)
#pragma unroll
        for (int nf = 0; nf < 4; ++nf) s[mf][nf] = f32x4{0.f, 0.f, 0.f, 0.f};
#pragma unroll
      for (int kp = 0; kp < 2; ++kp)
#pragma unroll
        for (int nf = 0; nf < 4; ++nf) {
          bf16x8 kb = *(const bf16x8*)&KsB[(nf * 16 + lr) * 80 + kp * 32 + g * 8];
#pragma unroll
          for (int mf = 0; mf < 2; ++mf)
            s[mf][nf] = __builtin_amdgcn_mfma_f32_16x16x32_bf16(kb, qf[mf][kp],
                                                                s[mf][nf], 0, 0, 0);
        }
#pragma unroll
      for (int nf = 0; nf < 4; ++nf) {
        bf16x8 kb = *(const bf16x8*)&KsB[(nf * 16 + lr) * 80 + 64 + (g & 1) * 8];
#pragma unroll
        for (int mf = 0; mf < 2; ++mf)
          s[mf][nf] = __builtin_amdgcn_mfma_f32_16x16x32_bf16(kb, qf2[mf],
                                                              s[mf][nf], 0, 0, 0);
      }

      // ---- softmax; element (mf,nf,r): k = kvbase+nf*16+g*4+r, q = wmin+mf*16+lr
      const bool maskT = (kvbase + 63 > wmin);
      if (maskT) {
        const int kb0 = kvbase + g * 4;
        const int qq = wmin + lr;
#pragma unroll
        for (int mf = 0; mf < 2; ++mf)
#pragma unroll
          for (int nf = 0; nf < 4; ++nf)
#pragma unroll
            for (int r = 0; r < 4; ++r)
              if (kb0 + nf * 16 + r > qq + mf * 16) s[mf][nf][r] = -INFINITY;
      }
      float mt[2];
#pragma unroll
      for (int mf = 0; mf < 2; ++mf) {
        float a = fmaxf(fmaxf(s[mf][0][0], s[mf][0][1]), fmaxf(s[mf][0][2], s[mf][0][3]));
        float b2 = fmaxf(fmaxf(s[mf][1][0], s[mf][1][1]), fmaxf(s[mf][1][2], s[mf][1][3]));
        float c = fmaxf(fmaxf(s[mf][2][0], s[mf][2][1]), fmaxf(s[mf][2][2], s[mf][2][3]));
        float d = fmaxf(fmaxf(s[mf][3][0], s[mf][3][1]), fmaxf(s[mf][3][2], s[mf][3][3]));
        float m = fmaxf(fmaxf(a, b2), fmaxf(c, d));
        m = fmaxf(m, __shfl_xor(m, 16, 64));
        m = fmaxf(m, __shfl_xor(m, 32, 64));
        mt[mf] = m;
      }
      int ok = (mt[0] <= m_r[0] + 10.0f) && (mt[1] <= m_r[1] + 10.0f);
      const bool need = !__all(ok);     // defer-max (T13)
      float fr[2];
      if (need) {
#pragma unroll
        for (int mf = 0; mf < 2; ++mf) {
          float mn = fmaxf(m_r[mf], mt[mf]);
          fr[mf] = exp2f(m_r[mf] - mn);
          m_r[mf] = mn;
        }
      }
      float lt[2] = {0.f, 0.f};
#pragma unroll
      for (int mf = 0; mf < 2; ++mf)
#pragma unroll
        for (int nf = 0; nf < 4; ++nf)
#pragma unroll
          for (int r = 0; r < 4; ++r) {
            float p = exp2f(s[mf][nf][r] - m_r[mf]);
            s[mf][nf][r] = p;
            lt[mf] += p;
          }
#pragma unroll
      for (int mf = 0; mf < 2; ++mf) {
        lt[mf] += __shfl_xor(lt[mf], 16, 64);
        lt[mf] += __shfl_xor(lt[mf], 32, 64);
      }
      if (need) {
#pragma unroll
        for (int mf = 0; mf < 2; ++mf) {
          l_r[mf] = l_r[mf] * fr[mf] + lt[mf];
#pragma unroll
          for (int r = 0; r < 4; ++r) {
            float fro = __shfl(fr[mf], g * 4 + r, 64);
#pragma unroll
            for (int of = 0; of < 5; ++of) o_acc[mf][of][r] *= fro;
          }
        }
      } else {
        l_r[0] += lt[0];
        l_r[1] += lt[1];
      }

      // ---- P^T -> Ps[q][k] (integer pack: low half = even k) ----
#pragma unroll
      for (int mf = 0; mf < 2; ++mf)
#pragma unroll
        for (int nf = 0; nf < 4; ++nf) {
          unsigned w0 = (unsigned)f2b(s[mf][nf][0]) |
                        ((unsigned)f2b(s[mf][nf][1]) << 16);
          unsigned w1 = (unsigned)f2b(s[mf][nf][2]) |
                        ((unsigned)f2b(s[mf][nf][3]) << 16);
          unsigned* dst = (unsigned*)&PsW[(mf * 16 + lr) * 72 + nf * 16 + g * 4];
          dst[0] = w0;
          dst[1] = w1;
        }

      // ---- O += P V : 20 MFMA ----
      const unsigned short* VtB = Vt[bufI];
#pragma unroll
      for (int kk = 0; kk < 2; ++kk) {
        bf16x8 pa[2];
#pragma unroll
        for (int mf = 0; mf < 2; ++mf)
          pa[mf] = *(const bf16x8*)&PsW[(mf * 16 + lr) * 72 + kk * 32 + g * 8];
#pragma unroll
        for (int of = 0; of < 5; ++of) {
          bf16x8 vv = *(const bf16x8*)&VtB[(of * 16 + lr) * 72 + kk * 32 + g * 8];
#pragma unroll
          for (int mf = 0; mf < 2; ++mf)
            o_acc[mf][of] = __builtin_amdgcn_mfma_f32_16x16x32_bf16(
                pa[mf], vv, o_acc[mf][of], 0, 0, 0);
        }
      }
    }
    __syncthreads();
  }
#undef STAGE_KV

  // ---- epilogue: O[b][row][h*80 + d] ----
#pragma unroll
  for (int mf = 0; mf < 2; ++mf) {
    float linv = 1.0f / l_r[mf];
#pragma unroll
    for (int r = 0; r < 4; ++r) {
      float li = __shfl(linv, g * 4 + r, 64);
      int row = wmin + mf * 16 + g * 4 + r;
#pragma unroll
      for (int of = 0; of < 5; ++of)
        o[((size_t)b * 1024 + row) * 1280 + h * 80 + of * 16 + lr] =
            f2b(o_acc[mf][of][r] * li);
    }
  }
}

// ---------------- launcher ----------------
extern "C" void kernel_launch(void* const* d_in, const int* in_sizes, int n_in,
                              void* d_out, int out_size, void* d_ws, size_t ws_size,
                              hipStream_t stream) {
  const float* X     = (const float*)d_in[0];
  const float* rp    = (const float*)d_in[1];
  const float* Wqkv  = (const float*)d_in[2];
  const float* bqkv  = (const float*)d_in[3];
  const float* Wproj = (const float*)d_in[4];
  const float* bproj = (const float*)d_in[5];
  float* out = (float*)d_out;

  char* ws = (char*)d_ws;
  unsigned short* Xb     = (unsigned short*)(ws);              // 20971520 B (reused as Ob)
  unsigned short* Wqkvt  = (unsigned short*)(ws + 20971520);   // 9830400 B
  unsigned short* Wprojt = (unsigned short*)(ws + 30801920);   // 3276800 B
  float*          cosT   = (float*)(ws + 34078720);            // 163840 B
  float*          sinT   = (float*)(ws + 34242560);            // 163840 B
  unsigned short* vb     = (unsigned short*)(ws + 34406400);   // 20971520 B (V^T)
  unsigned short* qb     = (unsigned short*)d_out;             // q,k live in d_out until proj
  unsigned short* kb     = qb + 10485760;
  unsigned short* Ob     = Xb;

  convert_bf16x4<<<10240, 256, 0, stream>>>(X, Xb, 2621440);
  transpose_f2b<<<dim3(120, 40), 256, 0, stream>>>(Wqkv, Wqkvt, 1280, 3840);
  transpose_f2b<<<dim3(40, 40), 256, 0, stream>>>(Wproj, Wprojt, 1280, 1280);
  rope_table<<<160, 256, 0, stream>>>(rp, cosT, sinT, 40960);
  gemm256<0><<<480, 512, 0, stream>>>(Xb, Wqkvt, bqkv, qb, kb, vb,
                                      nullptr, 8192, 3840, 1280);
  rope_apply<<<5120, 256, 0, stream>>>(qb, kb, cosT, sinT);
  attn_fwd<<<512, 512, 0, stream>>>(qb, kb, vb, Ob);
  gemm128<1><<<640, 256, 0, stream>>>(Ob, Wprojt, bproj, out, 8192, 1280, 1280);
}